// Round 5
// baseline (460.930 us; speedup 1.0000x reference)
//
#include <hip/hip_runtime.h>
#include <hip/hip_bf16.h>

typedef __attribute__((ext_vector_type(8))) short short8;   // 8 x bf16 (MFMA A/B frag)
typedef __attribute__((ext_vector_type(4))) float f32x4;    // MFMA C/D frag

using bf16 = __hip_bfloat16;

static constexpr int B_ = 2, S_ = 2048, HID_ = 2048, NH_ = 16;
static constexpr int ROPE_ = 64, VDIM_ = 128, QHEAD_ = 128;
static constexpr int QLORA_ = 682, KVLORA_ = 256;
static constexpr int QLORA_P = 704;   // K padded to mult of 64
static constexpr int NQA_P = 768;     // q_a N padded
static constexpr int NKVA_P = 384;    // kv_a N padded
static constexpr int NA_ = NQA_P + NKVA_P;   // 1152 merged down-proj N
static constexpr float THETA_ = 128000.0f;
static constexpr float SCALE_ = 0.08838834764831845f;  // 1/sqrt(128)
static constexpr float SCL2_ = 0.08838834764831845f * 1.4426950408889634f; // fold log2e
static constexpr float EPS_ = 1e-6f;
static constexpr int BS_ = B_ * S_;   // 4096

// async global->LDS, 16B per lane. Dest must be linear in lane order
// (wave-uniform base + lane*16); source is per-lane (may be swizzled/gathered).
__device__ __forceinline__ void gl2lds16(const void* g, void* l) {
    __builtin_amdgcn_global_load_lds(
        (const __attribute__((address_space(1))) unsigned int*)g,
        (__attribute__((address_space(3))) unsigned int*)l, 16, 0, 0);
}

struct bf16x4_s { bf16 x, y, z, w; };

// ---------------- merged prep: weight transposes + x convert + rope table -----
struct TD { const float* src; bf16* dst; int Ksrc, Nsrc, Kpad, tilesX, off, perm; };
struct TDs { TD d[5]; };
static constexpr int PREP_TILES = 8576;          // transpose tile-blocks

__global__ void k_prep(TDs P, const float* __restrict__ x, bf16* __restrict__ xb,
                       float* __restrict__ ct, float* __restrict__ st) {
    __shared__ float tile[32][33];
    if (blockIdx.x >= PREP_TILES) {              // misc path
        int bid = blockIdx.x - PREP_TILES;
        int t = threadIdx.y * 32 + threadIdx.x;
        if (bid < 8192) {                        // convert BS*HID f32 -> bf16, 4/thread
            int i = bid * 256 + t;
            float4 v = reinterpret_cast<const float4*>(x)[i];
            bf16x4_s o;
            o.x = __float2bfloat16(v.x); o.y = __float2bfloat16(v.y);
            o.z = __float2bfloat16(v.z); o.w = __float2bfloat16(v.w);
            reinterpret_cast<bf16x4_s*>(xb)[i] = o;
        } else {                                 // rope table [S][32]
            int idx = (bid - 8192) * 256 + t;    // S*32 = 65536
            int tpos = idx >> 5, j = idx & 31;
            float inv = expf(-(float)j * (logf(THETA_) / 32.0f));
            float f = (float)tpos * inv;
            ct[idx] = cosf(f);
            st[idx] = sinf(f);
        }
        return;
    }
    int flat = blockIdx.x;
    int di = 0;
    #pragma unroll
    for (int i = 1; i < 5; ++i) if (flat >= P.d[i].off) di = i;
    TD d = P.d[di];
    int local = flat - d.off;
    int xt = local % d.tilesX, yt = local / d.tilesX;
    int kb = xt * 32, nb = yt * 32;
    int tx = threadIdx.x, ty = threadIdx.y;          // 32 x 8
    #pragma unroll
    for (int i = 0; i < 32; i += 8) {
        int k = kb + ty + i, n = nb + tx;
        tile[ty + i][tx] = (k < d.Ksrc && n < d.Nsrc) ? d.src[(size_t)k * d.Nsrc + n] : 0.0f;
    }
    __syncthreads();
    #pragma unroll
    for (int i = 0; i < 32; i += 8) {
        int n = nb + ty + i, k = kb + tx;
        int nd = n;
        if (d.perm) {                          // kv_b: h*192+(knope 64|v 128) -> [knope 1024 | v 2048]
            int h = n / 192, dd = n - h * 192;
            nd = (dd < 64) ? h * 64 + dd : 1024 + h * 128 + (dd - 64);
        }
        d.dst[(size_t)nd * d.Kpad + k] = __float2bfloat16(tile[tx][ty + i]);
    }
}

// ---------------- GEMM: C[M][N] = A[M][K] * Bt[N][K]^T  (bf16, f32 acc) -------
// 128x128 tile, BK=64, 4 waves (2x2), 4x4 16x16x32 frags/wave.
// LDS [128 rows][8 chunks of 16B], phys chunk = ch ^ (row&7). gl2lds staging.
#define GEMM_PROLOGUE(Aptr, Bptr, LDA, LDB, KDIM)                                        \
    __shared__ bf16 As[128 * 64];                                                        \
    __shared__ bf16 Bs[128 * 64];                                                        \
    const int t = threadIdx.x;                                                           \
    const int lane = t & 63, w = t >> 6;                                                 \
    const int l15 = lane & 15, l4 = lane >> 4;                                           \
    const int wr = (w >> 1) * 64, wc = (w & 1) * 64;                                     \
    const int m0 = blockIdx.y * 128, n0 = blockIdx.x * 128;                              \
    f32x4 acc[4][4] = {};                                                                \
    for (int k0 = 0; k0 < (KDIM); k0 += 64) {                                            \
        _Pragma("unroll")                                                                \
        for (int i = 0; i < 4; ++i) {                                                    \
            int cid = t + i * 256;                                                       \
            int row = cid >> 3;                                                          \
            int ch = (cid & 7) ^ (row & 7);                                              \
            gl2lds16((Aptr) + (size_t)(m0 + row) * (LDA) + k0 + ch * 8,                  \
                     reinterpret_cast<char*>(As) + cid * 16);                            \
            gl2lds16((Bptr) + (size_t)(n0 + row) * (LDB) + k0 + ch * 8,                  \
                     reinterpret_cast<char*>(Bs) + cid * 16);                            \
        }                                                                                \
        __syncthreads();                                                                 \
        _Pragma("unroll")                                                                \
        for (int kk = 0; kk < 2; ++kk) {                                                 \
            short8 a[4], b[4];                                                           \
            _Pragma("unroll")                                                            \
            for (int m = 0; m < 4; ++m) {                                                \
                int row = wr + m * 16 + l15;                                             \
                int ch = (kk * 4 + l4) ^ (row & 7);                                      \
                a[m] = *reinterpret_cast<const short8*>(                                 \
                    reinterpret_cast<const char*>(As) + row * 128 + ch * 16);            \
            }                                                                            \
            _Pragma("unroll")                                                            \
            for (int n = 0; n < 4; ++n) {                                                \
                int row = wc + n * 16 + l15;                                             \
                int ch = (kk * 4 + l4) ^ (row & 7);                                      \
                b[n] = *reinterpret_cast<const short8*>(                                 \
                    reinterpret_cast<const char*>(Bs) + row * 128 + ch * 16);            \
            }                                                                            \
            _Pragma("unroll")                                                            \
            for (int m = 0; m < 4; ++m)                                                  \
                _Pragma("unroll")                                                        \
                for (int n = 0; n < 4; ++n)                                              \
                    acc[m][n] = __builtin_amdgcn_mfma_f32_16x16x32_bf16(a[m], b[n],      \
                                                                       acc[m][n], 0, 0, 0); \
        }                                                                                \
        __syncthreads();                                                                 \
    }
// C/D layout: col = lane&15, row = (lane>>4)*4 + reg  [verified m89/m91]

template <typename OutT>
__launch_bounds__(256)
__global__ void gemm_bt(const bf16* __restrict__ A, const bf16* __restrict__ Bt,
                        OutT* __restrict__ C, int K, int lda, int ldb, int ldc)
{
    GEMM_PROLOGUE(A, Bt, lda, ldb, K)
    #pragma unroll
    for (int m = 0; m < 4; ++m)
        #pragma unroll
        for (int n = 0; n < 4; ++n)
            #pragma unroll
            for (int j = 0; j < 4; ++j) {
                int r = m0 + wr + m * 16 + l4 * 4 + j;
                int c = n0 + wc + n * 16 + l15;
                float v = acc[m][n][j];
                if constexpr (sizeof(OutT) == 2) C[(size_t)r * ldc + c] = __float2bfloat16(v);
                else                             C[(size_t)r * ldc + c] = v;
            }
}

// ---------------- q_b GEMM with fused RoPE + scale + (b,h,s,d) scatter --------
// N-tile == one head (128 cols). Waves with wc=0 hold nope cols, wc=64 pe cols.
// Q is pre-scaled by SCALE*log2e so flash softmax works directly in log2 domain.
__launch_bounds__(256)
__global__ void gemm_qb_rope(const bf16* __restrict__ A, const bf16* __restrict__ Bt,
                             const float* __restrict__ ct, const float* __restrict__ st,
                             bf16* __restrict__ Qf)
{
    GEMM_PROLOGUE(A, Bt, QLORA_P, QLORA_P, QLORA_P)
    const int h = blockIdx.x;                  // head
    if (wc == 0) {
        #pragma unroll
        for (int m = 0; m < 4; ++m)
            #pragma unroll
            for (int n = 0; n < 4; ++n)
                #pragma unroll
                for (int j = 0; j < 4; ++j) {
                    int r = m0 + wr + m * 16 + l4 * 4 + j;
                    int c = n * 16 + l15;                       // [0,64) nope
                    int s = r & (S_ - 1), bq = r >> 11;
                    Qf[((size_t)(bq * NH_ + h) * S_ + s) * 128 + c] =
                        __float2bfloat16(acc[m][n][j] * SCL2_);
                }
    } else {
        #pragma unroll
        for (int m = 0; m < 4; ++m)
            #pragma unroll
            for (int n = 0; n < 4; ++n)
                #pragma unroll
                for (int j = 0; j < 4; ++j) {
                    int r = m0 + wr + m * 16 + l4 * 4 + j;
                    int p = n * 16 + l15;                       // pe-local [0,64)
                    int jj = p >> 1, odd = p & 1;
                    float v = acc[m][n][j];
                    float pr = __shfl_xor(v, 1);
                    float e0 = odd ? pr : v, e1 = odd ? v : pr;
                    int s = r & (S_ - 1), bq = r >> 11;
                    float c_ = ct[s * 32 + jj], s_ = st[s * 32 + jj];
                    float ov = odd ? (e1 * c_ + e0 * s_) : (e0 * c_ - e1 * s_);
                    int c_out = 64 + (odd ? 32 : 0) + jj;
                    Qf[((size_t)(bq * NH_ + h) * S_ + s) * 128 + c_out] =
                        __float2bfloat16(ov * SCL2_);
                }
    }
}

// ---------------- kv_b GEMM (permuted weights): knope + direct-V^T epilogue ---
// n0 < 1024: k_nope -> knope[bs][1024]. n0 >= 1024: head tile -> Vt[bh][128][S].
__launch_bounds__(256)
__global__ void gemm_kvb_split(const bf16* __restrict__ A, const bf16* __restrict__ Bt,
                               bf16* __restrict__ knope, bf16* __restrict__ Vt)
{
    GEMM_PROLOGUE(A, Bt, KVLORA_, KVLORA_, KVLORA_)
    if (n0 < 1024) {
        #pragma unroll
        for (int m = 0; m < 4; ++m)
            #pragma unroll
            for (int n = 0; n < 4; ++n)
                #pragma unroll
                for (int j = 0; j < 4; ++j) {
                    int r = m0 + wr + m * 16 + l4 * 4 + j;
                    int c = n0 + wc + n * 16 + l15;
                    knope[(size_t)r * 1024 + c] = __float2bfloat16(acc[m][n][j]);
                }
    } else {
        const int h = (n0 - 1024) >> 7;
        const int bq = m0 >> 11;               // uniform per block (128-row tile)
        const int bh = bq * NH_ + h;
        #pragma unroll
        for (int m = 0; m < 4; ++m)
            #pragma unroll
            for (int n = 0; n < 4; ++n) {
                int cl = wc + n * 16 + l15;    // d within head
                int rb = m0 + wr + m * 16 + l4 * 4;
                int s = rb & (S_ - 1);
                ushort4 pk;
                {
                    bf16 h0 = __float2bfloat16(acc[m][n][0]);
                    bf16 h1 = __float2bfloat16(acc[m][n][1]);
                    bf16 h2 = __float2bfloat16(acc[m][n][2]);
                    bf16 h3 = __float2bfloat16(acc[m][n][3]);
                    pk.x = *reinterpret_cast<unsigned short*>(&h0);
                    pk.y = *reinterpret_cast<unsigned short*>(&h1);
                    pk.z = *reinterpret_cast<unsigned short*>(&h2);
                    pk.w = *reinterpret_cast<unsigned short*>(&h3);
                }
                *reinterpret_cast<ushort4*>(Vt + ((size_t)bh * 128 + cl) * S_ + s) = pk;
            }
    }
}

// ---------------- fused rmsnorm(q_a), rmsnorm(ckv), rope(k_pe) ----------------
__launch_bounds__(256)
__global__ void k_rms_rope(const bf16* __restrict__ qac,
                           const float* __restrict__ qln, const float* __restrict__ kvln,
                           const float* __restrict__ ct, const float* __restrict__ st,
                           bf16* __restrict__ qan, bf16* __restrict__ ckvn, bf16* __restrict__ kr)
{
    __shared__ float red[8];
    int bs = blockIdx.x;
    int t = threadIdx.x, lane = t & 63, w = t >> 6;
    int s = bs & (S_ - 1);
    const bf16* qrow = qac + (size_t)bs * NA_;
    const bf16* crow = qrow + NQA_P;
    float sq = 0.f, sk;
    for (int c = t; c < QLORA_; c += 256) { float v = __bfloat162float(qrow[c]); sq += v * v; }
    { float v = __bfloat162float(crow[t]); sk = v * v; }          // t in [0,256) covers all
    #pragma unroll
    for (int m = 1; m < 64; m <<= 1) { sq += __shfl_xor(sq, m); sk += __shfl_xor(sk, m); }
    if (lane == 0) { red[w] = sq; red[4 + w] = sk; }
    __syncthreads();
    sq = red[0] + red[1] + red[2] + red[3];
    sk = red[4] + red[5] + red[6] + red[7];
    float qs = rsqrtf(sq / (float)QLORA_ + EPS_);
    float ks = rsqrtf(sk / (float)KVLORA_ + EPS_);
    for (int c = t; c < QLORA_P; c += 256)
        qan[(size_t)bs * QLORA_P + c] =
            (c < QLORA_) ? __float2bfloat16(__bfloat162float(qrow[c]) * qs * qln[c])
                         : __float2bfloat16(0.0f);
    ckvn[(size_t)bs * KVLORA_ + t] = __float2bfloat16(__bfloat162float(crow[t]) * ks * kvln[t]);
    if (t < 64) {
        int j = t & 31;
        float c_ = ct[s * 32 + j], s_ = st[s * 32 + j];
        float e0 = __bfloat162float(crow[KVLORA_ + 2 * j]);      // de-interleaved RoPE
        float e1 = __bfloat162float(crow[KVLORA_ + 2 * j + 1]);
        float v = (t < 32) ? (e0 * c_ - e1 * s_) : (e1 * c_ + e0 * s_);
        kr[(size_t)bs * 64 + t] = __float2bfloat16(v);
    }
}

// ---------------- causal flash attention --------------------------------------
// block = 128 q-rows x (b,h). 8 waves, each owns 16 q-rows. Q in registers
// (pre-scaled by SCALE*log2e). K gathered from knope+kr; V from Vt.
// Single-buffered K/V -> LDS 48 KiB -> 3 blocks/CU; cross-block overlap (m114)
// replaces intra-block prefetch. Heavy qb blocks dispatch first.
__launch_bounds__(512, 6)
__global__ void k_flash(const bf16* __restrict__ Qf, const bf16* __restrict__ knope,
                        const bf16* __restrict__ kr, const bf16* __restrict__ Vt,
                        bf16* __restrict__ attn_out)
{
    __shared__ bf16 Ks[64 * 128];         // [64 k-rows][16 chunks], swz ch^(row&7)
    __shared__ bf16 Vs[128 * 64];         // [128 d-rows][8 chunks]
    __shared__ bf16 Ps[8][16 * 64];       // per-wave P strip [16 rows][8 chunks]

    const int t = threadIdx.x, lane = t & 63, w = t >> 6;
    const int l15 = lane & 15, l4 = lane >> 4;
    // heavy-first: y=0..7 -> qb 15..8 (launched first), y=8..15 -> qb 0..7
    const int qb = (blockIdx.y < 8) ? (15 - blockIdx.y) : (blockIdx.y - 8);
    const int bh = blockIdx.x;
    const int q0 = qb * 128;
    const int b = bh >> 4, h = bh & 15;
    const int r0 = q0 + w * 16;           // wave's first q-row

    // Q -> registers (one-time strided read; L2/L3 absorbs)
    short8 qa_[4];
    {
        const bf16* qrow = Qf + ((size_t)bh * S_ + r0 + l15) * 128;
        #pragma unroll
        for (int kk = 0; kk < 4; ++kk)
            qa_[kk] = *reinterpret_cast<const short8*>(qrow + kk * 32 + l4 * 8);
    }

    // hoisted per-lane staging sources (advance by constant stride per tile)
    const bf16 *kSrc0, *kSrc1, *vSrc0, *vSrc1;
    size_t kStp0, kStp1;
    {
        int cid = t, row = cid >> 4, ch = (cid & 15) ^ (row & 7);
        kSrc0 = (ch < 8) ? knope + (size_t)(b * S_ + row) * 1024 + h * 64 + ch * 8
                         : kr + (size_t)(b * S_ + row) * 64 + (ch - 8) * 8;
        kStp0 = (ch < 8) ? (size_t)64 * 1024 : (size_t)64 * 64;
    }
    {
        int cid = t + 512, row = cid >> 4, ch = (cid & 15) ^ (row & 7);
        kSrc1 = (ch < 8) ? knope + (size_t)(b * S_ + row) * 1024 + h * 64 + ch * 8
                         : kr + (size_t)(b * S_ + row) * 64 + (ch - 8) * 8;
        kStp1 = (ch < 8) ? (size_t)64 * 1024 : (size_t)64 * 64;
    }
    {
        const bf16* Vg = Vt + (size_t)bh * 128 * S_;
        int cid = t, row = cid >> 3, ch = (cid & 7) ^ (row & 7);
        vSrc0 = Vg + (size_t)row * S_ + ch * 8;
        cid = t + 512; row = cid >> 3; ch = (cid & 7) ^ (row & 7);
        vSrc1 = Vg + (size_t)row * S_ + ch * 8;
    }
    auto stage = [&]() {
        gl2lds16(kSrc0, reinterpret_cast<char*>(Ks) + t * 16);
        gl2lds16(kSrc1, reinterpret_cast<char*>(Ks) + (t + 512) * 16);
        gl2lds16(vSrc0, reinterpret_cast<char*>(Vs) + t * 16);
        gl2lds16(vSrc1, reinterpret_cast<char*>(Vs) + (t + 512) * 16);
        kSrc0 += kStp0; kSrc1 += kStp1; vSrc0 += 64; vSrc1 += 64;
    };

    const int NT = qb * 2 + 2;                     // 64-wide K tiles
    stage();

    f32x4 o[8] = {};
    float m_r[4], l_r[4];
    #pragma unroll
    for (int j = 0; j < 4; ++j) { m_r[j] = -1e30f; l_r[j] = 0.f; }

    for (int kb = 0; kb < NT; ++kb) {
        const int k0 = kb * 64;
        __syncthreads();                           // staged loads landed, all waves ready

        if (k0 <= r0 + 15) {                       // skip fully-masked tiles for this wave
            // S strip = Q(16x128) @ K^T(128x64)  (already in log2 domain via Q scale)
            f32x4 sfr[4] = {};
            __builtin_amdgcn_s_setprio(1);
            #pragma unroll
            for (int kk = 0; kk < 4; ++kk) {
                short8 bfr[4];
                #pragma unroll
                for (int n = 0; n < 4; ++n) {
                    int row = n * 16 + l15;
                    int ch = (kk * 4 + l4) ^ (row & 7);
                    bfr[n] = *reinterpret_cast<const short8*>(
                        reinterpret_cast<const char*>(Ks) + row * 256 + ch * 16);
                }
                #pragma unroll
                for (int n = 0; n < 4; ++n)
                    sfr[n] = __builtin_amdgcn_mfma_f32_16x16x32_bf16(qa_[kk], bfr[n], sfr[n], 0, 0, 0);
            }
            __builtin_amdgcn_s_setprio(0);

            const bool needMask = (k0 + 63 > r0);
            if (needMask) {
                #pragma unroll
                for (int n = 0; n < 4; ++n)
                    #pragma unroll
                    for (int j = 0; j < 4; ++j) {
                        int col = k0 + n * 16 + l15;
                        int row = r0 + l4 * 4 + j;
                        if (col > row) sfr[n][j] = -1e30f;
                    }
            }

            // online max with defer-rescale (T13, THR=8 in log2 domain)
            float rm[4];
            bool grow = false;
            #pragma unroll
            for (int j = 0; j < 4; ++j) {
                float r = fmaxf(fmaxf(sfr[0][j], sfr[1][j]), fmaxf(sfr[2][j], sfr[3][j]));
                r = fmaxf(r, __shfl_xor(r, 1));
                r = fmaxf(r, __shfl_xor(r, 2));
                r = fmaxf(r, __shfl_xor(r, 4));
                r = fmaxf(r, __shfl_xor(r, 8));
                rm[j] = r;
                grow |= (r > m_r[j] + 8.0f);
            }
            if (__ballot(grow)) {
                #pragma unroll
                for (int j = 0; j < 4; ++j) {
                    float mn = fmaxf(m_r[j], rm[j]);
                    float alpha = exp2f(m_r[j] - mn);
                    m_r[j] = mn;
                    l_r[j] *= alpha;
                    #pragma unroll
                    for (int n = 0; n < 8; ++n) o[n][j] *= alpha;
                }
            }

            char* pb = reinterpret_cast<char*>(Ps[w]);
            #pragma unroll
            for (int j = 0; j < 4; ++j) {
                float rs = 0.f;
                #pragma unroll
                for (int n = 0; n < 4; ++n) {
                    float p = exp2f(sfr[n][j] - m_r[j]);
                    sfr[n][j] = p;
                    rs += p;
                }
                rs += __shfl_xor(rs, 1); rs += __shfl_xor(rs, 2);
                rs += __shfl_xor(rs, 4); rs += __shfl_xor(rs, 8);
                l_r[j] += rs;
                int row = l4 * 4 + j;
                #pragma unroll
                for (int n = 0; n < 4; ++n) {
                    int col = n * 16 + l15;
                    int ch = (col >> 3) ^ (row & 7);
                    *reinterpret_cast<bf16*>(pb + row * 128 + ch * 16 + (col & 7) * 2) =
                        __float2bfloat16(sfr[n][j]);
                }
            }
            // O += P(16x64) @ V(64x128)
            __builtin_amdgcn_s_setprio(1);
            #pragma unroll
            for (int kk = 0; kk < 2; ++kk) {
                int pch = (kk * 4 + l4) ^ (l15 & 7);
                short8 pa = *reinterpret_cast<const short8*>(pb + l15 * 128 + pch * 16);
                #pragma unroll
                for (int n = 0; n < 8; ++n) {
                    int row = n * 16 + l15;
                    int ch = (kk * 4 + l4) ^ (row & 7);
                    short8 vb = *reinterpret_cast<const short8*>(
                        reinterpret_cast<const char*>(Vs) + row * 128 + ch * 16);
                    o[n] = __builtin_amdgcn_mfma_f32_16x16x32_bf16(pa, vb, o[n], 0, 0, 0);
                }
            }
            __builtin_amdgcn_s_setprio(0);
        }
        __syncthreads();                           // all waves done reading Ks/Vs
        if (kb + 1 < NT) stage();                  // overwrite for next tile
    }

    size_t obase = ((size_t)(b * S_) + q0 + w * 16) * (size_t)(NH_ * VDIM_) + h * VDIM_;
    #pragma unroll
    for (int n = 0; n < 8; ++n)
        #pragma unroll
        for (int j = 0; j < 4; ++j) {
            int r = l4 * 4 + j;
            int c = n * 16 + l15;
            attn_out[obase + (size_t)r * (NH_ * VDIM_) + c] = __float2bfloat16(o[n][j] / l_r[j]);
        }
}

// ==============================================================================
extern "C" void kernel_launch(void* const* d_in, const int* in_sizes, int n_in,
                              void* d_out, int out_size, void* d_ws, size_t ws_size,
                              hipStream_t stream)
{
    (void)in_sizes; (void)n_in; (void)out_size;
    const float* x       = (const float*)d_in[0];
    const float* q_a_w   = (const float*)d_in[1];
    const float* q_a_ln  = (const float*)d_in[2];
    const float* q_b_w   = (const float*)d_in[3];
    const float* kv_a_w  = (const float*)d_in[4];
    const float* kv_a_ln = (const float*)d_in[5];
    const float* kv_b_w  = (const float*)d_in[6];
    const float* o_w     = (const float*)d_in[7];
    float* out = (float*)d_out;

    char* ws = (char*)d_ws;
    size_t off = 0;
    auto alloc = [&](size_t bytes) -> char* {
        char* p = ws + off;
        off += (bytes + 255) & ~(size_t)255;
        return p;
    };

    bf16* xb     = (bf16*)alloc((size_t)BS_ * HID_ * 2);        // reused as Qf after gemm_a
    bf16* a_wt   = (bf16*)alloc((size_t)NA_ * HID_ * 2);        // merged [q_a | kv_a]^T
    bf16* qb_wt  = (bf16*)alloc((size_t)2048 * QLORA_P * 2);
    bf16* kvb_wt = (bf16*)alloc((size_t)3072 * KVLORA_ * 2);    // permuted cols
    bf16* ow_t   = (bf16*)alloc((size_t)2048 * 2048 * 2);
    float* ct    = (float*)alloc((size_t)S_ * 32 * 4);
    float* st    = (float*)alloc((size_t)S_ * 32 * 4);
    bf16* qac    = (bf16*)alloc((size_t)BS_ * NA_ * 2);         // down-proj out [qa|ckvkpe]
    bf16* qan    = (bf16*)alloc((size_t)BS_ * QLORA_P * 2);
    bf16* ckvn   = (bf16*)alloc((size_t)BS_ * KVLORA_ * 2);
    bf16* kr     = (bf16*)alloc((size_t)BS_ * 64 * 2);
    bf16* knope  = (bf16*)alloc((size_t)BS_ * 1024 * 2);
    bf16* Vt     = (bf16*)alloc((size_t)BS_ * 2048 * 2);        // [bh][128][S]
    bf16* attn   = (bf16*)alloc((size_t)BS_ * 2048 * 2);

    bf16* Qf = xb;   // xb dead after gemm_a

    if (ws_size < off) return;  // diagnostic guard: absmax would stay exactly 3.468750

    // stage 0: merged prep (weight transposes + x convert + rope tables)
    TDs P;
    //              src      dst                    Ksrc  Nsrc  Kpad  tX  off   perm
    P.d[0] = TD{ q_a_w,  a_wt,                      2048,  682, 2048, 64,    0, 0 };  // 64x24
    P.d[1] = TD{ kv_a_w, a_wt + (size_t)NQA_P*2048, 2048,  320, 2048, 64, 1536, 0 };  // 64x12
    P.d[2] = TD{ q_b_w,  qb_wt,                      682, 2048,  704, 22, 2304, 0 };  // 22x64
    P.d[3] = TD{ kv_b_w, kvb_wt,                     256, 3072,  256,  8, 3712, 1 };  // 8x96
    P.d[4] = TD{ o_w,    ow_t,                      2048, 2048, 2048, 64, 4480, 0 };  // 64x64
    k_prep<<<PREP_TILES + 8192 + 256, dim3(32, 8), 0, stream>>>(P, x, xb, ct, st);

    // stage 1: merged down-projection  qac = x @ [q_a|kv_a]
    gemm_bt<bf16><<<dim3(NA_ / 128, BS_ / 128), 256, 0, stream>>>(xb, a_wt, qac,
                                                                  HID_, HID_, HID_, NA_);

    // stage 2: rmsnorms + k_pe rope
    k_rms_rope<<<BS_, 256, 0, stream>>>(qac, q_a_ln, kv_a_ln, ct, st, qan, ckvn, kr);

    // stage 3: up-projections with fused epilogues
    gemm_qb_rope<<<dim3(2048 / 128, BS_ / 128), 256, 0, stream>>>(qan, qb_wt, ct, st, Qf);
    gemm_kvb_split<<<dim3(3072 / 128, BS_ / 128), 256, 0, stream>>>(ckvn, kvb_wt, knope, Vt);

    // stage 4: causal flash attention (heavy-first qb order)
    k_flash<<<dim3(B_ * NH_, S_ / 128), 512, 0, stream>>>(Qf, knope, kr, Vt, attn);

    // stage 5: output projection (f32 out)
    gemm_bt<float><<<dim3(2048 / 128, BS_ / 128), 256, 0, stream>>>(attn, ow_t, out,
                                                                    HID_, HID_, HID_, 2048);
}

// Round 6
// 264.765 us; speedup vs baseline: 1.7409x; 1.7409x over previous
//
#include <hip/hip_runtime.h>
#include <hip/hip_bf16.h>

typedef __attribute__((ext_vector_type(8))) short short8;   // 8 x bf16 (MFMA A/B frag)
typedef __attribute__((ext_vector_type(4))) float f32x4;    // MFMA C/D frag

using bf16 = __hip_bfloat16;

static constexpr int B_ = 2, S_ = 2048, HID_ = 2048, NH_ = 16;
static constexpr int ROPE_ = 64, VDIM_ = 128, QHEAD_ = 128;
static constexpr int QLORA_ = 682, KVLORA_ = 256;
static constexpr int QLORA_P = 704;   // K padded to mult of 64
static constexpr int NQA_P = 768;     // q_a N padded
static constexpr int NKVA_P = 384;    // kv_a N padded
static constexpr int NA_ = NQA_P + NKVA_P;   // 1152 merged down-proj N
static constexpr float THETA_ = 128000.0f;
static constexpr float SCALE_ = 0.08838834764831845f;  // 1/sqrt(128)
static constexpr float SCL2_ = 0.08838834764831845f * 1.4426950408889634f; // fold log2e
static constexpr float EPS_ = 1e-6f;
static constexpr int BS_ = B_ * S_;   // 4096

// async global->LDS, 16B per lane. Dest must be linear in lane order
// (wave-uniform base + lane*16); source is per-lane (may be swizzled/gathered).
__device__ __forceinline__ void gl2lds16(const void* g, void* l) {
    __builtin_amdgcn_global_load_lds(
        (const __attribute__((address_space(1))) unsigned int*)g,
        (__attribute__((address_space(3))) unsigned int*)l, 16, 0, 0);
}

struct bf16x4_s { bf16 x, y, z, w; };

// ---------------- merged prep: weight transposes + x convert + rope table -----
struct TD { const float* src; bf16* dst; int Ksrc, Nsrc, Kpad, tilesX, off, perm; };
struct TDs { TD d[5]; };
static constexpr int PREP_TILES = 8576;          // transpose tile-blocks

__global__ void k_prep(TDs P, const float* __restrict__ x, bf16* __restrict__ xb,
                       float* __restrict__ ct, float* __restrict__ st) {
    __shared__ float tile[32][33];
    if (blockIdx.x >= PREP_TILES) {              // misc path
        int bid = blockIdx.x - PREP_TILES;
        int t = threadIdx.y * 32 + threadIdx.x;
        if (bid < 8192) {                        // convert BS*HID f32 -> bf16, 4/thread
            int i = bid * 256 + t;
            float4 v = reinterpret_cast<const float4*>(x)[i];
            bf16x4_s o;
            o.x = __float2bfloat16(v.x); o.y = __float2bfloat16(v.y);
            o.z = __float2bfloat16(v.z); o.w = __float2bfloat16(v.w);
            reinterpret_cast<bf16x4_s*>(xb)[i] = o;
        } else {                                 // rope table [S][32]
            int idx = (bid - 8192) * 256 + t;    // S*32 = 65536
            int tpos = idx >> 5, j = idx & 31;
            float inv = expf(-(float)j * (logf(THETA_) / 32.0f));
            float f = (float)tpos * inv;
            ct[idx] = cosf(f);
            st[idx] = sinf(f);
        }
        return;
    }
    int flat = blockIdx.x;
    int di = 0;
    #pragma unroll
    for (int i = 1; i < 5; ++i) if (flat >= P.d[i].off) di = i;
    TD d = P.d[di];
    int local = flat - d.off;
    int xt = local % d.tilesX, yt = local / d.tilesX;
    int kb = xt * 32, nb = yt * 32;
    int tx = threadIdx.x, ty = threadIdx.y;          // 32 x 8
    #pragma unroll
    for (int i = 0; i < 32; i += 8) {
        int k = kb + ty + i, n = nb + tx;
        tile[ty + i][tx] = (k < d.Ksrc && n < d.Nsrc) ? d.src[(size_t)k * d.Nsrc + n] : 0.0f;
    }
    __syncthreads();
    #pragma unroll
    for (int i = 0; i < 32; i += 8) {
        int n = nb + ty + i, k = kb + tx;
        int nd = n;
        if (d.perm) {                          // kv_b: h*192+(knope 64|v 128) -> [knope 1024 | v 2048]
            int h = n / 192, dd = n - h * 192;
            nd = (dd < 64) ? h * 64 + dd : 1024 + h * 128 + (dd - 64);
        }
        d.dst[(size_t)nd * d.Kpad + k] = __float2bfloat16(tile[tx][ty + i]);
    }
}

// ---------------- GEMM: C[M][N] = A[M][K] * Bt[N][K]^T  (bf16, f32 acc) -------
// 128x128 tile, BK=64, 4 waves (2x2), 4x4 16x16x32 frags/wave.
// LDS [128 rows][8 chunks of 16B], phys chunk = ch ^ (row&7). gl2lds staging.
#define GEMM_PROLOGUE(Aptr, Bptr, LDA, LDB, KDIM)                                        \
    __shared__ bf16 As[128 * 64];                                                        \
    __shared__ bf16 Bs[128 * 64];                                                        \
    const int t = threadIdx.x;                                                           \
    const int lane = t & 63, w = t >> 6;                                                 \
    const int l15 = lane & 15, l4 = lane >> 4;                                           \
    const int wr = (w >> 1) * 64, wc = (w & 1) * 64;                                     \
    const int m0 = blockIdx.y * 128, n0 = blockIdx.x * 128;                              \
    f32x4 acc[4][4] = {};                                                                \
    for (int k0 = 0; k0 < (KDIM); k0 += 64) {                                            \
        _Pragma("unroll")                                                                \
        for (int i = 0; i < 4; ++i) {                                                    \
            int cid = t + i * 256;                                                       \
            int row = cid >> 3;                                                          \
            int ch = (cid & 7) ^ (row & 7);                                              \
            gl2lds16((Aptr) + (size_t)(m0 + row) * (LDA) + k0 + ch * 8,                  \
                     reinterpret_cast<char*>(As) + cid * 16);                            \
            gl2lds16((Bptr) + (size_t)(n0 + row) * (LDB) + k0 + ch * 8,                  \
                     reinterpret_cast<char*>(Bs) + cid * 16);                            \
        }                                                                                \
        __syncthreads();                                                                 \
        _Pragma("unroll")                                                                \
        for (int kk = 0; kk < 2; ++kk) {                                                 \
            short8 a[4], b[4];                                                           \
            _Pragma("unroll")                                                            \
            for (int m = 0; m < 4; ++m) {                                                \
                int row = wr + m * 16 + l15;                                             \
                int ch = (kk * 4 + l4) ^ (row & 7);                                      \
                a[m] = *reinterpret_cast<const short8*>(                                 \
                    reinterpret_cast<const char*>(As) + row * 128 + ch * 16);            \
            }                                                                            \
            _Pragma("unroll")                                                            \
            for (int n = 0; n < 4; ++n) {                                                \
                int row = wc + n * 16 + l15;                                             \
                int ch = (kk * 4 + l4) ^ (row & 7);                                      \
                b[n] = *reinterpret_cast<const short8*>(                                 \
                    reinterpret_cast<const char*>(Bs) + row * 128 + ch * 16);            \
            }                                                                            \
            _Pragma("unroll")                                                            \
            for (int m = 0; m < 4; ++m)                                                  \
                _Pragma("unroll")                                                        \
                for (int n = 0; n < 4; ++n)                                              \
                    acc[m][n] = __builtin_amdgcn_mfma_f32_16x16x32_bf16(a[m], b[n],      \
                                                                       acc[m][n], 0, 0, 0); \
        }                                                                                \
        __syncthreads();                                                                 \
    }
// C/D layout: col = lane&15, row = (lane>>4)*4 + reg  [verified m89/m91]

template <typename OutT>
__launch_bounds__(256)
__global__ void gemm_bt(const bf16* __restrict__ A, const bf16* __restrict__ Bt,
                        OutT* __restrict__ C, int K, int lda, int ldb, int ldc)
{
    GEMM_PROLOGUE(A, Bt, lda, ldb, K)
    #pragma unroll
    for (int m = 0; m < 4; ++m)
        #pragma unroll
        for (int n = 0; n < 4; ++n)
            #pragma unroll
            for (int j = 0; j < 4; ++j) {
                int r = m0 + wr + m * 16 + l4 * 4 + j;
                int c = n0 + wc + n * 16 + l15;
                float v = acc[m][n][j];
                if constexpr (sizeof(OutT) == 2) C[(size_t)r * ldc + c] = __float2bfloat16(v);
                else                             C[(size_t)r * ldc + c] = v;
            }
}

// ---------------- q_b GEMM with fused RoPE + scale + (b,h,s,d) scatter --------
// N-tile == one head (128 cols). Waves with wc=0 hold nope cols, wc=64 pe cols.
// Q is pre-scaled by SCALE*log2e so flash softmax works directly in log2 domain.
__launch_bounds__(256)
__global__ void gemm_qb_rope(const bf16* __restrict__ A, const bf16* __restrict__ Bt,
                             const float* __restrict__ ct, const float* __restrict__ st,
                             bf16* __restrict__ Qf)
{
    GEMM_PROLOGUE(A, Bt, QLORA_P, QLORA_P, QLORA_P)
    const int h = blockIdx.x;                  // head
    if (wc == 0) {
        #pragma unroll
        for (int m = 0; m < 4; ++m)
            #pragma unroll
            for (int n = 0; n < 4; ++n)
                #pragma unroll
                for (int j = 0; j < 4; ++j) {
                    int r = m0 + wr + m * 16 + l4 * 4 + j;
                    int c = n * 16 + l15;                       // [0,64) nope
                    int s = r & (S_ - 1), bq = r >> 11;
                    Qf[((size_t)(bq * NH_ + h) * S_ + s) * 128 + c] =
                        __float2bfloat16(acc[m][n][j] * SCL2_);
                }
    } else {
        #pragma unroll
        for (int m = 0; m < 4; ++m)
            #pragma unroll
            for (int n = 0; n < 4; ++n)
                #pragma unroll
                for (int j = 0; j < 4; ++j) {
                    int r = m0 + wr + m * 16 + l4 * 4 + j;
                    int p = n * 16 + l15;                       // pe-local [0,64)
                    int jj = p >> 1, odd = p & 1;
                    float v = acc[m][n][j];
                    float pr = __shfl_xor(v, 1);
                    float e0 = odd ? pr : v, e1 = odd ? v : pr;
                    int s = r & (S_ - 1), bq = r >> 11;
                    float c_ = ct[s * 32 + jj], s_ = st[s * 32 + jj];
                    float ov = odd ? (e1 * c_ + e0 * s_) : (e0 * c_ - e1 * s_);
                    int c_out = 64 + (odd ? 32 : 0) + jj;
                    Qf[((size_t)(bq * NH_ + h) * S_ + s) * 128 + c_out] =
                        __float2bfloat16(ov * SCL2_);
                }
    }
}

// ---------------- kv_b GEMM (permuted weights): knope + direct-V^T epilogue ---
// n0 < 1024: k_nope -> knope[bs][1024]. n0 >= 1024: head tile -> Vt[bh][128][S].
__launch_bounds__(256)
__global__ void gemm_kvb_split(const bf16* __restrict__ A, const bf16* __restrict__ Bt,
                               bf16* __restrict__ knope, bf16* __restrict__ Vt)
{
    GEMM_PROLOGUE(A, Bt, KVLORA_, KVLORA_, KVLORA_)
    if (n0 < 1024) {
        #pragma unroll
        for (int m = 0; m < 4; ++m)
            #pragma unroll
            for (int n = 0; n < 4; ++n)
                #pragma unroll
                for (int j = 0; j < 4; ++j) {
                    int r = m0 + wr + m * 16 + l4 * 4 + j;
                    int c = n0 + wc + n * 16 + l15;
                    knope[(size_t)r * 1024 + c] = __float2bfloat16(acc[m][n][j]);
                }
    } else {
        const int h = (n0 - 1024) >> 7;
        const int bq = m0 >> 11;               // uniform per block (128-row tile)
        const int bh = bq * NH_ + h;
        #pragma unroll
        for (int m = 0; m < 4; ++m)
            #pragma unroll
            for (int n = 0; n < 4; ++n) {
                int cl = wc + n * 16 + l15;    // d within head
                int rb = m0 + wr + m * 16 + l4 * 4;
                int s = rb & (S_ - 1);
                ushort4 pk;
                {
                    bf16 h0 = __float2bfloat16(acc[m][n][0]);
                    bf16 h1 = __float2bfloat16(acc[m][n][1]);
                    bf16 h2 = __float2bfloat16(acc[m][n][2]);
                    bf16 h3 = __float2bfloat16(acc[m][n][3]);
                    pk.x = *reinterpret_cast<unsigned short*>(&h0);
                    pk.y = *reinterpret_cast<unsigned short*>(&h1);
                    pk.z = *reinterpret_cast<unsigned short*>(&h2);
                    pk.w = *reinterpret_cast<unsigned short*>(&h3);
                }
                *reinterpret_cast<ushort4*>(Vt + ((size_t)bh * 128 + cl) * S_ + s) = pk;
            }
    }
}

// ---------------- fused rmsnorm(q_a), rmsnorm(ckv), rope(k_pe) ----------------
__launch_bounds__(256)
__global__ void k_rms_rope(const bf16* __restrict__ qac,
                           const float* __restrict__ qln, const float* __restrict__ kvln,
                           const float* __restrict__ ct, const float* __restrict__ st,
                           bf16* __restrict__ qan, bf16* __restrict__ ckvn, bf16* __restrict__ kr)
{
    __shared__ float red[8];
    int bs = blockIdx.x;
    int t = threadIdx.x, lane = t & 63, w = t >> 6;
    int s = bs & (S_ - 1);
    const bf16* qrow = qac + (size_t)bs * NA_;
    const bf16* crow = qrow + NQA_P;
    float sq = 0.f, sk;
    for (int c = t; c < QLORA_; c += 256) { float v = __bfloat162float(qrow[c]); sq += v * v; }
    { float v = __bfloat162float(crow[t]); sk = v * v; }          // t in [0,256) covers all
    #pragma unroll
    for (int m = 1; m < 64; m <<= 1) { sq += __shfl_xor(sq, m); sk += __shfl_xor(sk, m); }
    if (lane == 0) { red[w] = sq; red[4 + w] = sk; }
    __syncthreads();
    sq = red[0] + red[1] + red[2] + red[3];
    sk = red[4] + red[5] + red[6] + red[7];
    float qs = rsqrtf(sq / (float)QLORA_ + EPS_);
    float ks = rsqrtf(sk / (float)KVLORA_ + EPS_);
    for (int c = t; c < QLORA_P; c += 256)
        qan[(size_t)bs * QLORA_P + c] =
            (c < QLORA_) ? __float2bfloat16(__bfloat162float(qrow[c]) * qs * qln[c])
                         : __float2bfloat16(0.0f);
    ckvn[(size_t)bs * KVLORA_ + t] = __float2bfloat16(__bfloat162float(crow[t]) * ks * kvln[t]);
    if (t < 64) {
        int j = t & 31;
        float c_ = ct[s * 32 + j], s_ = st[s * 32 + j];
        float e0 = __bfloat162float(crow[KVLORA_ + 2 * j]);      // de-interleaved RoPE
        float e1 = __bfloat162float(crow[KVLORA_ + 2 * j + 1]);
        float v = (t < 32) ? (e0 * c_ - e1 * s_) : (e1 * c_ + e0 * s_);
        kr[(size_t)bs * 64 + t] = __float2bfloat16(v);
    }
}

// ---------------- causal flash attention --------------------------------------
// block = 128 q-rows x (b,h). 8 waves, each owns 16 q-rows. Q in registers
// (pre-scaled by SCALE*log2e). K gathered from knope+kr; V from Vt.
// Double-buffered K/V, one barrier per tile (R4 structure, proven 111us).
// LDS 80 KiB -> 2 blocks/CU. VGPR must stay ~64: bounds (512,4), NOT 6 (R5
// lesson: waves/EU=6 caps VGPR at 85 -> compiler spills -> 215MB scratch writes).
// Heavy qb blocks dispatch first (makespan).
__launch_bounds__(512, 4)
__global__ void k_flash(const bf16* __restrict__ Qf, const bf16* __restrict__ knope,
                        const bf16* __restrict__ kr, const bf16* __restrict__ Vt,
                        bf16* __restrict__ attn_out)
{
    __shared__ bf16 Ks[2][64 * 128];      // [64 k-rows][16 chunks], swz ch^(row&7)
    __shared__ bf16 Vs[2][128 * 64];      // [128 d-rows][8 chunks]
    __shared__ bf16 Ps[8][16 * 64];       // per-wave P strip [16 rows][8 chunks]

    const int t = threadIdx.x, lane = t & 63, w = t >> 6;
    const int l15 = lane & 15, l4 = lane >> 4;
    // heavy-first: y=0..7 -> qb 15..8 (launched first), y=8..15 -> qb 0..7
    const int qb = (blockIdx.y < 8) ? (15 - blockIdx.y) : (blockIdx.y - 8);
    const int bh = blockIdx.x;
    const int q0 = qb * 128;
    const int b = bh >> 4, h = bh & 15;
    const int r0 = q0 + w * 16;           // wave's first q-row

    // Q -> registers (one-time strided read; L2/L3 absorbs). Pre-scaled.
    short8 qa_[4];
    {
        const bf16* qrow = Qf + ((size_t)bh * S_ + r0 + l15) * 128;
        #pragma unroll
        for (int kk = 0; kk < 4; ++kk)
            qa_[kk] = *reinterpret_cast<const short8*>(qrow + kk * 32 + l4 * 8);
    }

    // hoisted per-lane staging sources (advance by constant stride per tile)
    const bf16 *kSrc0, *kSrc1, *vSrc0, *vSrc1;
    size_t kStp0, kStp1;
    {
        int cid = t, row = cid >> 4, ch = (cid & 15) ^ (row & 7);
        kSrc0 = (ch < 8) ? knope + (size_t)(b * S_ + row) * 1024 + h * 64 + ch * 8
                         : kr + (size_t)(b * S_ + row) * 64 + (ch - 8) * 8;
        kStp0 = (ch < 8) ? (size_t)64 * 1024 : (size_t)64 * 64;
    }
    {
        int cid = t + 512, row = cid >> 4, ch = (cid & 15) ^ (row & 7);
        kSrc1 = (ch < 8) ? knope + (size_t)(b * S_ + row) * 1024 + h * 64 + ch * 8
                         : kr + (size_t)(b * S_ + row) * 64 + (ch - 8) * 8;
        kStp1 = (ch < 8) ? (size_t)64 * 1024 : (size_t)64 * 64;
    }
    {
        const bf16* Vg = Vt + (size_t)bh * 128 * S_;
        int cid = t, row = cid >> 3, ch = (cid & 7) ^ (row & 7);
        vSrc0 = Vg + (size_t)row * S_ + ch * 8;
        cid = t + 512; row = cid >> 3; ch = (cid & 7) ^ (row & 7);
        vSrc1 = Vg + (size_t)row * S_ + ch * 8;
    }
    auto stage = [&](int buf) {
        gl2lds16(kSrc0, reinterpret_cast<char*>(Ks[buf]) + t * 16);
        gl2lds16(kSrc1, reinterpret_cast<char*>(Ks[buf]) + (t + 512) * 16);
        gl2lds16(vSrc0, reinterpret_cast<char*>(Vs[buf]) + t * 16);
        gl2lds16(vSrc1, reinterpret_cast<char*>(Vs[buf]) + (t + 512) * 16);
        kSrc0 += kStp0; kSrc1 += kStp1; vSrc0 += 64; vSrc1 += 64;
    };

    const int NT = qb * 2 + 2;                     // 64-wide K tiles
    stage(0);
    __syncthreads();

    f32x4 o[8] = {};
    float m_r[4], l_r[4];
    #pragma unroll
    for (int j = 0; j < 4; ++j) { m_r[j] = -1e30f; l_r[j] = 0.f; }

    int cur = 0;
    for (int kb = 0; kb < NT; ++kb) {
        const int k0 = kb * 64;
        if (kb + 1 < NT) stage(cur ^ 1);           // next-tile loads fly under compute

        if (k0 <= r0 + 15) {                       // skip fully-masked tiles for this wave
            // S strip = Q(16x128) @ K^T(128x64)  (log2 domain via pre-scaled Q)
            f32x4 sfr[4] = {};
            __builtin_amdgcn_s_setprio(1);
            #pragma unroll
            for (int kk = 0; kk < 4; ++kk) {
                short8 bfr[4];
                #pragma unroll
                for (int n = 0; n < 4; ++n) {
                    int row = n * 16 + l15;
                    int ch = (kk * 4 + l4) ^ (row & 7);
                    bfr[n] = *reinterpret_cast<const short8*>(
                        reinterpret_cast<const char*>(Ks[cur]) + row * 256 + ch * 16);
                }
                #pragma unroll
                for (int n = 0; n < 4; ++n)
                    sfr[n] = __builtin_amdgcn_mfma_f32_16x16x32_bf16(qa_[kk], bfr[n], sfr[n], 0, 0, 0);
            }
            __builtin_amdgcn_s_setprio(0);

            const bool needMask = (k0 + 63 > r0);
            if (needMask) {
                #pragma unroll
                for (int n = 0; n < 4; ++n)
                    #pragma unroll
                    for (int j = 0; j < 4; ++j) {
                        int col = k0 + n * 16 + l15;
                        int row = r0 + l4 * 4 + j;
                        if (col > row) sfr[n][j] = -1e30f;
                    }
            }

            // online max with defer-rescale (T13, THR=8 in log2 domain)
            float rm[4];
            bool grow = false;
            #pragma unroll
            for (int j = 0; j < 4; ++j) {
                float r = fmaxf(fmaxf(sfr[0][j], sfr[1][j]), fmaxf(sfr[2][j], sfr[3][j]));
                r = fmaxf(r, __shfl_xor(r, 1));
                r = fmaxf(r, __shfl_xor(r, 2));
                r = fmaxf(r, __shfl_xor(r, 4));
                r = fmaxf(r, __shfl_xor(r, 8));
                rm[j] = r;
                grow |= (r > m_r[j] + 8.0f);
            }
            if (__ballot(grow)) {
                #pragma unroll
                for (int j = 0; j < 4; ++j) {
                    float mn = fmaxf(m_r[j], rm[j]);
                    float alpha = exp2f(m_r[j] - mn);
                    m_r[j] = mn;
                    l_r[j] *= alpha;
                    #pragma unroll
                    for (int n = 0; n < 8; ++n) o[n][j] *= alpha;
                }
            }

            char* pb = reinterpret_cast<char*>(Ps[w]);
            #pragma unroll
            for (int j = 0; j < 4; ++j) {
                float rs = 0.f;
                #pragma unroll
                for (int n = 0; n < 4; ++n) {
                    float p = exp2f(sfr[n][j] - m_r[j]);
                    sfr[n][j] = p;
                    rs += p;
                }
                rs += __shfl_xor(rs, 1); rs += __shfl_xor(rs, 2);
                rs += __shfl_xor(rs, 4); rs += __shfl_xor(rs, 8);
                l_r[j] += rs;
                int row = l4 * 4 + j;
                #pragma unroll
                for (int n = 0; n < 4; ++n) {
                    int col = n * 16 + l15;
                    int ch = (col >> 3) ^ (row & 7);
                    *reinterpret_cast<bf16*>(pb + row * 128 + ch * 16 + (col & 7) * 2) =
                        __float2bfloat16(sfr[n][j]);
                }
            }
            // O += P(16x64) @ V(64x128)
            __builtin_amdgcn_s_setprio(1);
            #pragma unroll
            for (int kk = 0; kk < 2; ++kk) {
                int pch = (kk * 4 + l4) ^ (l15 & 7);
                short8 pa = *reinterpret_cast<const short8*>(pb + l15 * 128 + pch * 16);
                #pragma unroll
                for (int n = 0; n < 8; ++n) {
                    int row = n * 16 + l15;
                    int ch = (kk * 4 + l4) ^ (row & 7);
                    short8 vb = *reinterpret_cast<const short8*>(
                        reinterpret_cast<const char*>(Vs[cur]) + row * 128 + ch * 16);
                    o[n] = __builtin_amdgcn_mfma_f32_16x16x32_bf16(pa, vb, o[n], 0, 0, 0);
                }
            }
            __builtin_amdgcn_s_setprio(0);
        }
        __syncthreads();     // drains next-tile loads (they flew under compute) + syncs
        cur ^= 1;
    }

    size_t obase = ((size_t)(b * S_) + q0 + w * 16) * (size_t)(NH_ * VDIM_) + h * VDIM_;
    #pragma unroll
    for (int n = 0; n < 8; ++n)
        #pragma unroll
        for (int j = 0; j < 4; ++j) {
            int r = l4 * 4 + j;
            int c = n * 16 + l15;
            attn_out[obase + (size_t)r * (NH_ * VDIM_) + c] = __float2bfloat16(o[n][j] / l_r[j]);
        }
}

// ==============================================================================
extern "C" void kernel_launch(void* const* d_in, const int* in_sizes, int n_in,
                              void* d_out, int out_size, void* d_ws, size_t ws_size,
                              hipStream_t stream)
{
    (void)in_sizes; (void)n_in; (void)out_size;
    const float* x       = (const float*)d_in[0];
    const float* q_a_w   = (const float*)d_in[1];
    const float* q_a_ln  = (const float*)d_in[2];
    const float* q_b_w   = (const float*)d_in[3];
    const float* kv_a_w  = (const float*)d_in[4];
    const float* kv_a_ln = (const float*)d_in[5];
    const float* kv_b_w  = (const float*)d_in[6];
    const float* o_w     = (const float*)d_in[7];
    float* out = (float*)d_out;

    char* ws = (char*)d_ws;
    size_t off = 0;
    auto alloc = [&](size_t bytes) -> char* {
        char* p = ws + off;
        off += (bytes + 255) & ~(size_t)255;
        return p;
    };

    bf16* xb     = (bf16*)alloc((size_t)BS_ * HID_ * 2);        // reused as Qf after gemm_a
    bf16* a_wt   = (bf16*)alloc((size_t)NA_ * HID_ * 2);        // merged [q_a | kv_a]^T
    bf16* qb_wt  = (bf16*)alloc((size_t)2048 * QLORA_P * 2);
    bf16* kvb_wt = (bf16*)alloc((size_t)3072 * KVLORA_ * 2);    // permuted cols
    bf16* ow_t   = (bf16*)alloc((size_t)2048 * 2048 * 2);
    float* ct    = (float*)alloc((size_t)S_ * 32 * 4);
    float* st    = (float*)alloc((size_t)S_ * 32 * 4);
    bf16* qac    = (bf16*)alloc((size_t)BS_ * NA_ * 2);         // down-proj out [qa|ckvkpe]
    bf16* qan    = (bf16*)alloc((size_t)BS_ * QLORA_P * 2);
    bf16* ckvn   = (bf16*)alloc((size_t)BS_ * KVLORA_ * 2);
    bf16* kr     = (bf16*)alloc((size_t)BS_ * 64 * 2);
    bf16* knope  = (bf16*)alloc((size_t)BS_ * 1024 * 2);
    bf16* Vt     = (bf16*)alloc((size_t)BS_ * 2048 * 2);        // [bh][128][S]
    bf16* attn   = (bf16*)alloc((size_t)BS_ * 2048 * 2);

    bf16* Qf = xb;   // xb dead after gemm_a

    if (ws_size < off) return;  // diagnostic guard: absmax would stay exactly 3.468750

    // stage 0: merged prep (weight transposes + x convert + rope tables)
    TDs P;
    //              src      dst                    Ksrc  Nsrc  Kpad  tX  off   perm
    P.d[0] = TD{ q_a_w,  a_wt,                      2048,  682, 2048, 64,    0, 0 };  // 64x24
    P.d[1] = TD{ kv_a_w, a_wt + (size_t)NQA_P*2048, 2048,  320, 2048, 64, 1536, 0 };  // 64x12
    P.d[2] = TD{ q_b_w,  qb_wt,                      682, 2048,  704, 22, 2304, 0 };  // 22x64
    P.d[3] = TD{ kv_b_w, kvb_wt,                     256, 3072,  256,  8, 3712, 1 };  // 8x96
    P.d[4] = TD{ o_w,    ow_t,                      2048, 2048, 2048, 64, 4480, 0 };  // 64x64
    k_prep<<<PREP_TILES + 8192 + 256, dim3(32, 8), 0, stream>>>(P, x, xb, ct, st);

    // stage 1: merged down-projection  qac = x @ [q_a|kv_a]
    gemm_bt<bf16><<<dim3(NA_ / 128, BS_ / 128), 256, 0, stream>>>(xb, a_wt, qac,
                                                                  HID_, HID_, HID_, NA_);

    // stage 2: rmsnorms + k_pe rope
    k_rms_rope<<<BS_, 256, 0, stream>>>(qac, q_a_ln, kv_a_ln, ct, st, qan, ckvn, kr);

    // stage 3: up-projections with fused epilogues
    gemm_qb_rope<<<dim3(2048 / 128, BS_ / 128), 256, 0, stream>>>(qan, qb_wt, ct, st, Qf);
    gemm_kvb_split<<<dim3(3072 / 128, BS_ / 128), 256, 0, stream>>>(ckvn, kvb_wt, knope, Vt);

    // stage 4: causal flash attention (heavy-first qb order, dbuf K/V)
    k_flash<<<dim3(B_ * NH_, S_ / 128), 512, 0, stream>>>(Qf, knope, kr, Vt, attn);

    // stage 5: output projection (f32 out)
    gemm_bt<float><<<dim3(2048 / 128, BS_ / 128), 256, 0, stream>>>(attn, ow_t, out,
                                                                    HID_, HID_, HID_, 2048);
}

// Round 7
// 229.481 us; speedup vs baseline: 2.0086x; 1.1538x over previous
//
#include <hip/hip_runtime.h>
#include <hip/hip_bf16.h>

typedef __attribute__((ext_vector_type(8))) short short8;   // 8 x bf16 (MFMA A/B frag)
typedef __attribute__((ext_vector_type(4))) float f32x4;    // MFMA C/D frag

using bf16 = __hip_bfloat16;

static constexpr int B_ = 2, S_ = 2048, HID_ = 2048, NH_ = 16;
static constexpr int ROPE_ = 64, VDIM_ = 128, QHEAD_ = 128;
static constexpr int QLORA_ = 682, KVLORA_ = 256;
static constexpr int QLORA_P = 704;   // K padded to mult of 64
static constexpr int NQA_P = 768;     // q_a N padded
static constexpr int NKVA_P = 384;    // kv_a N padded
static constexpr int NA_ = NQA_P + NKVA_P;   // 1152 merged down-proj N
static constexpr float THETA_ = 128000.0f;
static constexpr float SCALE_ = 0.08838834764831845f;  // 1/sqrt(128)
static constexpr float SCL2_ = 0.08838834764831845f * 1.4426950408889634f; // fold log2e
static constexpr float EPS_ = 1e-6f;
static constexpr int BS_ = B_ * S_;   // 4096

// async global->LDS, 16B per lane. Dest must be linear in lane order
// (wave-uniform base + lane*16); source is per-lane (may be swizzled/gathered).
__device__ __forceinline__ void gl2lds16(const void* g, void* l) {
    __builtin_amdgcn_global_load_lds(
        (const __attribute__((address_space(1))) unsigned int*)g,
        (__attribute__((address_space(3))) unsigned int*)l, 16, 0, 0);
}

struct bf16x4_s { bf16 x, y, z, w; };

// ---------------- merged prep: weight transposes + x convert + rope table -----
struct TD { const float* src; bf16* dst; int Ksrc, Nsrc, Kpad, tilesX, off, perm; };
struct TDs { TD d[5]; };
static constexpr int PREP_TILES = 8576;          // transpose tile-blocks

__global__ void k_prep(TDs P, const float* __restrict__ x, bf16* __restrict__ xb,
                       float* __restrict__ ct, float* __restrict__ st) {
    __shared__ float tile[32][33];
    if (blockIdx.x >= PREP_TILES) {              // misc path
        int bid = blockIdx.x - PREP_TILES;
        int t = threadIdx.y * 32 + threadIdx.x;
        if (bid < 8192) {                        // convert BS*HID f32 -> bf16, 4/thread
            int i = bid * 256 + t;
            float4 v = reinterpret_cast<const float4*>(x)[i];
            bf16x4_s o;
            o.x = __float2bfloat16(v.x); o.y = __float2bfloat16(v.y);
            o.z = __float2bfloat16(v.z); o.w = __float2bfloat16(v.w);
            reinterpret_cast<bf16x4_s*>(xb)[i] = o;
        } else {                                 // rope table [S][32]
            int idx = (bid - 8192) * 256 + t;    // S*32 = 65536
            int tpos = idx >> 5, j = idx & 31;
            float inv = expf(-(float)j * (logf(THETA_) / 32.0f));
            float f = (float)tpos * inv;
            ct[idx] = cosf(f);
            st[idx] = sinf(f);
        }
        return;
    }
    int flat = blockIdx.x;
    int di = 0;
    #pragma unroll
    for (int i = 1; i < 5; ++i) if (flat >= P.d[i].off) di = i;
    TD d = P.d[di];
    int local = flat - d.off;
    int xt = local % d.tilesX, yt = local / d.tilesX;
    int kb = xt * 32, nb = yt * 32;
    int tx = threadIdx.x, ty = threadIdx.y;          // 32 x 8
    #pragma unroll
    for (int i = 0; i < 32; i += 8) {
        int k = kb + ty + i, n = nb + tx;
        tile[ty + i][tx] = (k < d.Ksrc && n < d.Nsrc) ? d.src[(size_t)k * d.Nsrc + n] : 0.0f;
    }
    __syncthreads();
    #pragma unroll
    for (int i = 0; i < 32; i += 8) {
        int n = nb + ty + i, k = kb + tx;
        int nd = n;
        if (d.perm) {                          // kv_b: h*192+(knope 64|v 128) -> [knope 1024 | v 2048]
            int h = n / 192, dd = n - h * 192;
            nd = (dd < 64) ? h * 64 + dd : 1024 + h * 128 + (dd - 64);
        }
        d.dst[(size_t)nd * d.Kpad + k] = __float2bfloat16(tile[tx][ty + i]);
    }
}

// ---------------- GEMM core: C[M][N] = A[M][K] * Bt[N][K]^T  (bf16, f32 acc) --
// 128x128 tile, BK=64, 4 waves (2x2), 4x4 16x16x32 frags/wave.
// LDS [128 rows][8 chunks of 16B], phys chunk = ch ^ (row&7). gl2lds staging.
#define GEMM_VARS                                                                        \
    __shared__ bf16 As[128 * 64];                                                        \
    __shared__ bf16 Bs[128 * 64];                                                        \
    const int t = threadIdx.x;                                                           \
    const int lane = t & 63, w = t >> 6;                                                 \
    const int l15 = lane & 15, l4 = lane >> 4;                                           \
    const int wr = (w >> 1) * 64, wc = (w & 1) * 64;

#define GEMM_CORE(Aptr, Bptr, LDA, LDB, KDIM, M0V, N0V)                                  \
    const int m0 = (M0V), n0 = (N0V);                                                    \
    f32x4 acc[4][4] = {};                                                                \
    for (int k0 = 0; k0 < (KDIM); k0 += 64) {                                            \
        _Pragma("unroll")                                                                \
        for (int i = 0; i < 4; ++i) {                                                    \
            int cid = t + i * 256;                                                       \
            int row = cid >> 3;                                                          \
            int ch = (cid & 7) ^ (row & 7);                                              \
            gl2lds16((Aptr) + (size_t)(m0 + row) * (LDA) + k0 + ch * 8,                  \
                     reinterpret_cast<char*>(As) + cid * 16);                            \
            gl2lds16((Bptr) + (size_t)(n0 + row) * (LDB) + k0 + ch * 8,                  \
                     reinterpret_cast<char*>(Bs) + cid * 16);                            \
        }                                                                                \
        __syncthreads();                                                                 \
        _Pragma("unroll")                                                                \
        for (int kk = 0; kk < 2; ++kk) {                                                 \
            short8 a[4], b[4];                                                           \
            _Pragma("unroll")                                                            \
            for (int m = 0; m < 4; ++m) {                                                \
                int row = wr + m * 16 + l15;                                             \
                int ch = (kk * 4 + l4) ^ (row & 7);                                      \
                a[m] = *reinterpret_cast<const short8*>(                                 \
                    reinterpret_cast<const char*>(As) + row * 128 + ch * 16);            \
            }                                                                            \
            _Pragma("unroll")                                                            \
            for (int n = 0; n < 4; ++n) {                                                \
                int row = wc + n * 16 + l15;                                             \
                int ch = (kk * 4 + l4) ^ (row & 7);                                      \
                b[n] = *reinterpret_cast<const short8*>(                                 \
                    reinterpret_cast<const char*>(Bs) + row * 128 + ch * 16);            \
            }                                                                            \
            _Pragma("unroll")                                                            \
            for (int m = 0; m < 4; ++m)                                                  \
                _Pragma("unroll")                                                        \
                for (int n = 0; n < 4; ++n)                                              \
                    acc[m][n] = __builtin_amdgcn_mfma_f32_16x16x32_bf16(a[m], b[n],      \
                                                                       acc[m][n], 0, 0, 0); \
        }                                                                                \
        __syncthreads();                                                                 \
    }
// C/D layout: col = lane&15, row = (lane>>4)*4 + reg  [verified m89/m91]

template <typename OutT>
__launch_bounds__(256)
__global__ void gemm_bt(const bf16* __restrict__ A, const bf16* __restrict__ Bt,
                        OutT* __restrict__ C, int K, int lda, int ldb, int ldc)
{
    GEMM_VARS
    GEMM_CORE(A, Bt, lda, ldb, K, blockIdx.y * 128, blockIdx.x * 128)
    #pragma unroll
    for (int m = 0; m < 4; ++m)
        #pragma unroll
        for (int n = 0; n < 4; ++n)
            #pragma unroll
            for (int j = 0; j < 4; ++j) {
                int r = m0 + wr + m * 16 + l4 * 4 + j;
                int c = n0 + wc + n * 16 + l15;
                float v = acc[m][n][j];
                if constexpr (sizeof(OutT) == 2) C[(size_t)r * ldc + c] = __float2bfloat16(v);
                else                             C[(size_t)r * ldc + c] = v;
            }
}

// ---------------- merged up-projections (one dispatch) ------------------------
// blockIdx.x < 16: q_b GEMM + fused RoPE/scale/scatter (N-tile == one head).
// blockIdx.x >= 16: kv_b GEMM (permuted weights) -> knope + direct V^T.
__launch_bounds__(256)
__global__ void gemm_up(const bf16* __restrict__ qan, const bf16* __restrict__ qb_wt,
                        const float* __restrict__ ct, const float* __restrict__ st,
                        bf16* __restrict__ Qf,
                        const bf16* __restrict__ ckvn, const bf16* __restrict__ kvb_wt,
                        bf16* __restrict__ knope, bf16* __restrict__ Vt)
{
    GEMM_VARS
    if (blockIdx.x < 16) {
        GEMM_CORE(qan, qb_wt, QLORA_P, QLORA_P, QLORA_P, blockIdx.y * 128, blockIdx.x * 128)
        (void)n0;
        const int h = blockIdx.x;                  // head
        if (wc == 0) {
            #pragma unroll
            for (int m = 0; m < 4; ++m)
                #pragma unroll
                for (int n = 0; n < 4; ++n)
                    #pragma unroll
                    for (int j = 0; j < 4; ++j) {
                        int r = m0 + wr + m * 16 + l4 * 4 + j;
                        int c = n * 16 + l15;                       // [0,64) nope
                        int s = r & (S_ - 1), bq = r >> 11;
                        Qf[((size_t)(bq * NH_ + h) * S_ + s) * 128 + c] =
                            __float2bfloat16(acc[m][n][j] * SCL2_);
                    }
        } else {
            #pragma unroll
            for (int m = 0; m < 4; ++m)
                #pragma unroll
                for (int n = 0; n < 4; ++n)
                    #pragma unroll
                    for (int j = 0; j < 4; ++j) {
                        int r = m0 + wr + m * 16 + l4 * 4 + j;
                        int p = n * 16 + l15;                       // pe-local [0,64)
                        int jj = p >> 1, odd = p & 1;
                        float v = acc[m][n][j];
                        float pr = __shfl_xor(v, 1);
                        float e0 = odd ? pr : v, e1 = odd ? v : pr;
                        int s = r & (S_ - 1), bq = r >> 11;
                        float c_ = ct[s * 32 + jj], s_ = st[s * 32 + jj];
                        float ov = odd ? (e1 * c_ + e0 * s_) : (e0 * c_ - e1 * s_);
                        int c_out = 64 + (odd ? 32 : 0) + jj;
                        Qf[((size_t)(bq * NH_ + h) * S_ + s) * 128 + c_out] =
                            __float2bfloat16(ov * SCL2_);
                    }
        }
    } else {
        GEMM_CORE(ckvn, kvb_wt, KVLORA_, KVLORA_, KVLORA_, blockIdx.y * 128,
                  (blockIdx.x - 16) * 128)
        if (n0 < 1024) {
            #pragma unroll
            for (int m = 0; m < 4; ++m)
                #pragma unroll
                for (int n = 0; n < 4; ++n)
                    #pragma unroll
                    for (int j = 0; j < 4; ++j) {
                        int r = m0 + wr + m * 16 + l4 * 4 + j;
                        int c = n0 + wc + n * 16 + l15;
                        knope[(size_t)r * 1024 + c] = __float2bfloat16(acc[m][n][j]);
                    }
        } else {
            const int h = (n0 - 1024) >> 7;
            const int bq = m0 >> 11;               // uniform per block (128-row tile)
            const int bh = bq * NH_ + h;
            #pragma unroll
            for (int m = 0; m < 4; ++m)
                #pragma unroll
                for (int n = 0; n < 4; ++n) {
                    int cl = wc + n * 16 + l15;    // d within head
                    int rb = m0 + wr + m * 16 + l4 * 4;
                    int s = rb & (S_ - 1);
                    ushort4 pk;
                    {
                        bf16 h0 = __float2bfloat16(acc[m][n][0]);
                        bf16 h1 = __float2bfloat16(acc[m][n][1]);
                        bf16 h2 = __float2bfloat16(acc[m][n][2]);
                        bf16 h3 = __float2bfloat16(acc[m][n][3]);
                        pk.x = *reinterpret_cast<unsigned short*>(&h0);
                        pk.y = *reinterpret_cast<unsigned short*>(&h1);
                        pk.z = *reinterpret_cast<unsigned short*>(&h2);
                        pk.w = *reinterpret_cast<unsigned short*>(&h3);
                    }
                    *reinterpret_cast<ushort4*>(Vt + ((size_t)bh * 128 + cl) * S_ + s) = pk;
                }
        }
    }
}

// ---------------- fused rmsnorm(q_a), rmsnorm(ckv), rope(k_pe) ----------------
__launch_bounds__(256)
__global__ void k_rms_rope(const bf16* __restrict__ qac,
                           const float* __restrict__ qln, const float* __restrict__ kvln,
                           const float* __restrict__ ct, const float* __restrict__ st,
                           bf16* __restrict__ qan, bf16* __restrict__ ckvn, bf16* __restrict__ kr)
{
    __shared__ float red[8];
    int bs = blockIdx.x;
    int t = threadIdx.x, lane = t & 63, w = t >> 6;
    int s = bs & (S_ - 1);
    const bf16* qrow = qac + (size_t)bs * NA_;
    const bf16* crow = qrow + NQA_P;
    float sq = 0.f, sk;
    for (int c = t; c < QLORA_; c += 256) { float v = __bfloat162float(qrow[c]); sq += v * v; }
    { float v = __bfloat162float(crow[t]); sk = v * v; }          // t in [0,256) covers all
    #pragma unroll
    for (int m = 1; m < 64; m <<= 1) { sq += __shfl_xor(sq, m); sk += __shfl_xor(sk, m); }
    if (lane == 0) { red[w] = sq; red[4 + w] = sk; }
    __syncthreads();
    sq = red[0] + red[1] + red[2] + red[3];
    sk = red[4] + red[5] + red[6] + red[7];
    float qs = rsqrtf(sq / (float)QLORA_ + EPS_);
    float ks = rsqrtf(sk / (float)KVLORA_ + EPS_);
    for (int c = t; c < QLORA_P; c += 256)
        qan[(size_t)bs * QLORA_P + c] =
            (c < QLORA_) ? __float2bfloat16(__bfloat162float(qrow[c]) * qs * qln[c])
                         : __float2bfloat16(0.0f);
    ckvn[(size_t)bs * KVLORA_ + t] = __float2bfloat16(__bfloat162float(crow[t]) * ks * kvln[t]);
    if (t < 64) {
        int j = t & 31;
        float c_ = ct[s * 32 + j], s_ = st[s * 32 + j];
        float e0 = __bfloat162float(crow[KVLORA_ + 2 * j]);      // de-interleaved RoPE
        float e1 = __bfloat162float(crow[KVLORA_ + 2 * j + 1]);
        float v = (t < 32) ? (e0 * c_ - e1 * s_) : (e1 * c_ + e0 * s_);
        kr[(size_t)bs * 64 + t] = __float2bfloat16(v);
    }
}

// ---------------- causal flash attention --------------------------------------
// block = 128 q-rows x (b,h). 8 waves, each owns 16 q-rows. Q in registers
// (pre-scaled by SCALE*log2e). K gathered from knope+kr; V from Vt.
// Double-buffered K/V, one barrier per tile. LDS 80 KiB -> 2 blocks/CU.
// SWAPPED QK^T: sfr = mfma(K_frag, Q_frag) puts q-row in l15, 16 k's in-lane
// -> row reduce = in-lane tree + 2 shfl (vs 16 shfl), P-write = 4 ds_write_b64.
// VGPR must stay ~64: bounds (512,4) (R5 lesson: tighter bound -> spills).
__launch_bounds__(512, 4)
__global__ void k_flash(const bf16* __restrict__ Qf, const bf16* __restrict__ knope,
                        const bf16* __restrict__ kr, const bf16* __restrict__ Vt,
                        bf16* __restrict__ attn_out)
{
    __shared__ bf16 Ks[2][64 * 128];      // [64 k-rows][16 chunks], swz ch^(row&7)
    __shared__ bf16 Vs[2][128 * 64];      // [128 d-rows][8 chunks]
    __shared__ bf16 Ps[8][16 * 64];       // per-wave P strip [16 q-rows][64 k], swz

    const int t = threadIdx.x, lane = t & 63, w = t >> 6;
    const int l15 = lane & 15, l4 = lane >> 4;
    // heavy-first: y=0..7 -> qb 15..8 (launched first), y=8..15 -> qb 0..7
    const int qb = (blockIdx.y < 8) ? (15 - blockIdx.y) : (blockIdx.y - 8);
    const int bh = blockIdx.x;
    const int q0 = qb * 128;
    const int b = bh >> 4, h = bh & 15;
    const int r0 = q0 + w * 16;           // wave's first q-row

    // Q -> registers (one-time strided read; L2/L3 absorbs). Pre-scaled.
    short8 qa_[4];
    {
        const bf16* qrow = Qf + ((size_t)bh * S_ + r0 + l15) * 128;
        #pragma unroll
        for (int kk = 0; kk < 4; ++kk)
            qa_[kk] = *reinterpret_cast<const short8*>(qrow + kk * 32 + l4 * 8);
    }

    // hoisted per-lane staging sources (advance by constant stride per tile)
    const bf16 *kSrc0, *kSrc1, *vSrc0, *vSrc1;
    size_t kStp0, kStp1;
    {
        int cid = t, row = cid >> 4, ch = (cid & 15) ^ (row & 7);
        kSrc0 = (ch < 8) ? knope + (size_t)(b * S_ + row) * 1024 + h * 64 + ch * 8
                         : kr + (size_t)(b * S_ + row) * 64 + (ch - 8) * 8;
        kStp0 = (ch < 8) ? (size_t)64 * 1024 : (size_t)64 * 64;
    }
    {
        int cid = t + 512, row = cid >> 4, ch = (cid & 15) ^ (row & 7);
        kSrc1 = (ch < 8) ? knope + (size_t)(b * S_ + row) * 1024 + h * 64 + ch * 8
                         : kr + (size_t)(b * S_ + row) * 64 + (ch - 8) * 8;
        kStp1 = (ch < 8) ? (size_t)64 * 1024 : (size_t)64 * 64;
    }
    {
        const bf16* Vg = Vt + (size_t)bh * 128 * S_;
        int cid = t, row = cid >> 3, ch = (cid & 7) ^ (row & 7);
        vSrc0 = Vg + (size_t)row * S_ + ch * 8;
        cid = t + 512; row = cid >> 3; ch = (cid & 7) ^ (row & 7);
        vSrc1 = Vg + (size_t)row * S_ + ch * 8;
    }
    auto stage = [&](int buf) {
        gl2lds16(kSrc0, reinterpret_cast<char*>(Ks[buf]) + t * 16);
        gl2lds16(kSrc1, reinterpret_cast<char*>(Ks[buf]) + (t + 512) * 16);
        gl2lds16(vSrc0, reinterpret_cast<char*>(Vs[buf]) + t * 16);
        gl2lds16(vSrc1, reinterpret_cast<char*>(Vs[buf]) + (t + 512) * 16);
        kSrc0 += kStp0; kSrc1 += kStp1; vSrc0 += 64; vSrc1 += 64;
    };

    const int NT = qb * 2 + 2;                     // 64-wide K tiles
    stage(0);
    __syncthreads();

    f32x4 o[8] = {};
    float m_r = -1e30f, l_r = 0.f;                 // per-lane: q-row = r0 + l15

    int cur = 0;
    for (int kb = 0; kb < NT; ++kb) {
        const int k0 = kb * 64;
        if (kb + 1 < NT) stage(cur ^ 1);           // next-tile loads fly under compute

        if (k0 <= r0 + 15) {                       // skip fully-masked tiles for this wave
            // S^T strip = K(64x128) @ Q^T(128x16): lane holds q=r0+l15,
            // k = k0 + m*16 + l4*4 + j   (log2 domain via pre-scaled Q)
            f32x4 sfr[4] = {};
            __builtin_amdgcn_s_setprio(1);
            #pragma unroll
            for (int kk = 0; kk < 4; ++kk) {
                short8 kf[4];
                #pragma unroll
                for (int m = 0; m < 4; ++m) {
                    int row = m * 16 + l15;
                    int ch = (kk * 4 + l4) ^ (row & 7);
                    kf[m] = *reinterpret_cast<const short8*>(
                        reinterpret_cast<const char*>(Ks[cur]) + row * 256 + ch * 16);
                }
                #pragma unroll
                for (int m = 0; m < 4; ++m)
                    sfr[m] = __builtin_amdgcn_mfma_f32_16x16x32_bf16(kf[m], qa_[kk], sfr[m], 0, 0, 0);
            }
            __builtin_amdgcn_s_setprio(0);

            const int qrow = r0 + l15;
            if (k0 + 63 > r0) {                    // causal mask (k > q)
                #pragma unroll
                for (int m = 0; m < 4; ++m) {
                    int kbase = k0 + m * 16 + l4 * 4;
                    #pragma unroll
                    for (int j = 0; j < 4; ++j)
                        if (kbase + j > qrow) sfr[m][j] = -1e30f;
                }
            }

            // row max: in-lane tree over 16 + 2 shfl across the l4 group
            float rm;
            {
                float a0 = fmaxf(fmaxf(sfr[0][0], sfr[0][1]), fmaxf(sfr[0][2], sfr[0][3]));
                float a1 = fmaxf(fmaxf(sfr[1][0], sfr[1][1]), fmaxf(sfr[1][2], sfr[1][3]));
                float a2 = fmaxf(fmaxf(sfr[2][0], sfr[2][1]), fmaxf(sfr[2][2], sfr[2][3]));
                float a3 = fmaxf(fmaxf(sfr[3][0], sfr[3][1]), fmaxf(sfr[3][2], sfr[3][3]));
                rm = fmaxf(fmaxf(a0, a1), fmaxf(a2, a3));
            }
            rm = fmaxf(rm, __shfl_xor(rm, 16));
            rm = fmaxf(rm, __shfl_xor(rm, 32));

            // defer-rescale (T13, THR=8 in log2 domain)
            if (__ballot(rm > m_r + 8.0f)) {
                float mn = fmaxf(m_r, rm);
                float alpha = exp2f(m_r - mn);
                m_r = mn;
                l_r *= alpha;
                float aj[4];
                #pragma unroll
                for (int j = 0; j < 4; ++j) aj[j] = __shfl(alpha, l4 * 4 + j);
                #pragma unroll
                for (int n = 0; n < 8; ++n)
                    #pragma unroll
                    for (int j = 0; j < 4; ++j) o[n][j] *= aj[j];
            }

            // P = exp2(S - m), pack pairs, one ds_write_b64 per m-frag
            char* pb = reinterpret_cast<char*>(Ps[w]);
            float rs = 0.f;
            #pragma unroll
            for (int m = 0; m < 4; ++m) {
                float p0 = exp2f(sfr[m][0] - m_r);
                float p1 = exp2f(sfr[m][1] - m_r);
                float p2 = exp2f(sfr[m][2] - m_r);
                float p3 = exp2f(sfr[m][3] - m_r);
                rs += (p0 + p1) + (p2 + p3);
                union { __hip_bfloat162 h; unsigned int u; } cl, ch2;
                cl.h  = __float22bfloat162_rn(make_float2(p0, p1));
                ch2.h = __float22bfloat162_rn(make_float2(p2, p3));
                int kloc = m * 16 + l4 * 4;
                int chnk = (kloc >> 3) ^ (l15 & 7);
                uint2 pk2; pk2.x = cl.u; pk2.y = ch2.u;
                *reinterpret_cast<uint2*>(pb + l15 * 128 + chnk * 16 + (kloc & 7) * 2) = pk2;
            }
            rs += __shfl_xor(rs, 16);
            rs += __shfl_xor(rs, 32);
            l_r += rs;

            // O += P(16x64) @ V(64x128)   (layout identical to prior rounds)
            __builtin_amdgcn_s_setprio(1);
            #pragma unroll
            for (int kk = 0; kk < 2; ++kk) {
                int pch = (kk * 4 + l4) ^ (l15 & 7);
                short8 pa = *reinterpret_cast<const short8*>(pb + l15 * 128 + pch * 16);
                #pragma unroll
                for (int n = 0; n < 8; ++n) {
                    int row = n * 16 + l15;
                    int ch = (kk * 4 + l4) ^ (row & 7);
                    short8 vb = *reinterpret_cast<const short8*>(
                        reinterpret_cast<const char*>(Vs[cur]) + row * 128 + ch * 16);
                    o[n] = __builtin_amdgcn_mfma_f32_16x16x32_bf16(pa, vb, o[n], 0, 0, 0);
                }
            }
            __builtin_amdgcn_s_setprio(0);
        }
        __syncthreads();     // drains next-tile loads (they flew under compute) + syncs
        cur ^= 1;
    }

    // l_r lives at lane with l15 == q-local; o[n][j] is q-local = l4*4+j
    float lj[4];
    #pragma unroll
    for (int j = 0; j < 4; ++j) lj[j] = __shfl(l_r, l4 * 4 + j);
    size_t obase = ((size_t)(b * S_) + q0 + w * 16) * (size_t)(NH_ * VDIM_) + h * VDIM_;
    #pragma unroll
    for (int n = 0; n < 8; ++n)
        #pragma unroll
        for (int j = 0; j < 4; ++j) {
            int r = l4 * 4 + j;
            int c = n * 16 + l15;
            attn_out[obase + (size_t)r * (NH_ * VDIM_) + c] = __float2bfloat16(o[n][j] / lj[j]);
        }
}

// ==============================================================================
extern "C" void kernel_launch(void* const* d_in, const int* in_sizes, int n_in,
                              void* d_out, int out_size, void* d_ws, size_t ws_size,
                              hipStream_t stream)
{
    (void)in_sizes; (void)n_in; (void)out_size;
    const float* x       = (const float*)d_in[0];
    const float* q_a_w   = (const float*)d_in[1];
    const float* q_a_ln  = (const float*)d_in[2];
    const float* q_b_w   = (const float*)d_in[3];
    const float* kv_a_w  = (const float*)d_in[4];
    const float* kv_a_ln = (const float*)d_in[5];
    const float* kv_b_w  = (const float*)d_in[6];
    const float* o_w     = (const float*)d_in[7];
    float* out = (float*)d_out;

    char* ws = (char*)d_ws;
    size_t off = 0;
    auto alloc = [&](size_t bytes) -> char* {
        char* p = ws + off;
        off += (bytes + 255) & ~(size_t)255;
        return p;
    };

    bf16* xb     = (bf16*)alloc((size_t)BS_ * HID_ * 2);        // reused as Qf after gemm_a
    bf16* a_wt   = (bf16*)alloc((size_t)NA_ * HID_ * 2);        // merged [q_a | kv_a]^T
    bf16* qb_wt  = (bf16*)alloc((size_t)2048 * QLORA_P * 2);
    bf16* kvb_wt = (bf16*)alloc((size_t)3072 * KVLORA_ * 2);    // permuted cols
    bf16* ow_t   = (bf16*)alloc((size_t)2048 * 2048 * 2);
    float* ct    = (float*)alloc((size_t)S_ * 32 * 4);
    float* st    = (float*)alloc((size_t)S_ * 32 * 4);
    bf16* qac    = (bf16*)alloc((size_t)BS_ * NA_ * 2);         // down-proj out [qa|ckvkpe]
    bf16* qan    = (bf16*)alloc((size_t)BS_ * QLORA_P * 2);
    bf16* ckvn   = (bf16*)alloc((size_t)BS_ * KVLORA_ * 2);
    bf16* kr     = (bf16*)alloc((size_t)BS_ * 64 * 2);
    bf16* knope  = (bf16*)alloc((size_t)BS_ * 1024 * 2);
    bf16* Vt     = (bf16*)alloc((size_t)BS_ * 2048 * 2);        // [bh][128][S]
    bf16* attn   = (bf16*)alloc((size_t)BS_ * 2048 * 2);

    bf16* Qf = xb;   // xb dead after gemm_a

    if (ws_size < off) return;  // diagnostic guard: absmax would stay exactly 3.468750

    // stage 0: merged prep (weight transposes + x convert + rope tables)
    TDs P;
    //              src      dst                    Ksrc  Nsrc  Kpad  tX  off   perm
    P.d[0] = TD{ q_a_w,  a_wt,                      2048,  682, 2048, 64,    0, 0 };  // 64x24
    P.d[1] = TD{ kv_a_w, a_wt + (size_t)NQA_P*2048, 2048,  320, 2048, 64, 1536, 0 };  // 64x12
    P.d[2] = TD{ q_b_w,  qb_wt,                      682, 2048,  704, 22, 2304, 0 };  // 22x64
    P.d[3] = TD{ kv_b_w, kvb_wt,                     256, 3072,  256,  8, 3712, 1 };  // 8x96
    P.d[4] = TD{ o_w,    ow_t,                      2048, 2048, 2048, 64, 4480, 0 };  // 64x64
    k_prep<<<PREP_TILES + 8192 + 256, dim3(32, 8), 0, stream>>>(P, x, xb, ct, st);

    // stage 1: merged down-projection  qac = x @ [q_a|kv_a]
    gemm_bt<bf16><<<dim3(NA_ / 128, BS_ / 128), 256, 0, stream>>>(xb, a_wt, qac,
                                                                  HID_, HID_, HID_, NA_);

    // stage 2: rmsnorms + k_pe rope
    k_rms_rope<<<BS_, 256, 0, stream>>>(qac, q_a_ln, kv_a_ln, ct, st, qan, ckvn, kr);

    // stage 3: merged up-projections with fused epilogues (one dispatch)
    gemm_up<<<dim3(16 + 24, BS_ / 128), 256, 0, stream>>>(qan, qb_wt, ct, st, Qf,
                                                          ckvn, kvb_wt, knope, Vt);

    // stage 4: causal flash attention (heavy-first qb order, dbuf K/V, swapped QK)
    k_flash<<<dim3(B_ * NH_, S_ / 128), 512, 0, stream>>>(Qf, knope, kr, Vt, attn);

    // stage 5: output projection (f32 out)
    gemm_bt<float><<<dim3(2048 / 128, BS_ / 128), 256, 0, stream>>>(attn, ow_t, out,
                                                                    HID_, HID_, HID_, 2048);
}

// Round 8
// 225.423 us; speedup vs baseline: 2.0447x; 1.0180x over previous
//
#include <hip/hip_runtime.h>
#include <hip/hip_bf16.h>

typedef __attribute__((ext_vector_type(8))) short short8;   // 8 x bf16 (MFMA A/B frag)
typedef __attribute__((ext_vector_type(4))) float f32x4;    // MFMA C/D frag

using bf16 = __hip_bfloat16;

static constexpr int B_ = 2, S_ = 2048, HID_ = 2048, NH_ = 16;
static constexpr int ROPE_ = 64, VDIM_ = 128, QHEAD_ = 128;
static constexpr int QLORA_ = 682, KVLORA_ = 256;
static constexpr int QLORA_P = 704;   // K padded to mult of 64
static constexpr int NQA_P = 768;     // q_a N padded
static constexpr int NKVA_P = 384;    // kv_a N padded
static constexpr int NA_ = NQA_P + NKVA_P;   // 1152 merged down-proj N
static constexpr float THETA_ = 128000.0f;
static constexpr float SCALE_ = 0.08838834764831845f;  // 1/sqrt(128)
static constexpr float SCL2_ = 0.08838834764831845f * 1.4426950408889634f; // fold log2e
static constexpr float EPS_ = 1e-6f;
static constexpr int BS_ = B_ * S_;   // 4096

// async global->LDS, 16B per lane. Dest must be linear in lane order
// (wave-uniform base + lane*16); source is per-lane (may be swizzled/gathered).
__device__ __forceinline__ void gl2lds16(const void* g, void* l) {
    __builtin_amdgcn_global_load_lds(
        (const __attribute__((address_space(1))) unsigned int*)g,
        (__attribute__((address_space(3))) unsigned int*)l, 16, 0, 0);
}

struct bf16x4_s { bf16 x, y, z, w; };

__device__ __forceinline__ float bfLo(unsigned int u) { return __uint_as_float(u << 16); }
__device__ __forceinline__ float bfHi(unsigned int u) { return __uint_as_float(u & 0xffff0000u); }

// ---------------- merged prep: weight transposes + x convert + rope table -----
// colw != null: fold per-K column weight (rmsnorm ln weight) into the transposed
// matrix. Writes packed as uint (2 bf16) for 2x store coalescing.
struct TD { const float* src; bf16* dst; const float* colw;
            int Ksrc, Nsrc, Kpad, tilesX, off, perm; };
struct TDs { TD d[5]; };
static constexpr int PREP_TILES = 8576;          // transpose tile-blocks

__global__ void k_prep(TDs P, const float* __restrict__ x, bf16* __restrict__ xb,
                       float* __restrict__ ct, float* __restrict__ st) {
    __shared__ float tile[32][33];
    if (blockIdx.x >= PREP_TILES) {              // misc path
        int bid = blockIdx.x - PREP_TILES;
        int t = threadIdx.y * 32 + threadIdx.x;
        if (bid < 8192) {                        // convert BS*HID f32 -> bf16, 4/thread
            int i = bid * 256 + t;
            float4 v = reinterpret_cast<const float4*>(x)[i];
            bf16x4_s o;
            o.x = __float2bfloat16(v.x); o.y = __float2bfloat16(v.y);
            o.z = __float2bfloat16(v.z); o.w = __float2bfloat16(v.w);
            reinterpret_cast<bf16x4_s*>(xb)[i] = o;
        } else {                                 // rope table [S][32]
            int idx = (bid - 8192) * 256 + t;    // S*32 = 65536
            int tpos = idx >> 5, j = idx & 31;
            float inv = expf(-(float)j * (logf(THETA_) / 32.0f));
            float f = (float)tpos * inv;
            ct[idx] = cosf(f);
            st[idx] = sinf(f);
        }
        return;
    }
    int flat = blockIdx.x;
    int di = 0;
    #pragma unroll
    for (int i = 1; i < 5; ++i) if (flat >= P.d[i].off) di = i;
    TD d = P.d[di];
    int local = flat - d.off;
    int xt = local % d.tilesX, yt = local / d.tilesX;
    int kb = xt * 32, nb = yt * 32;
    int tx = threadIdx.x, ty = threadIdx.y;          // 32 x 8
    #pragma unroll
    for (int i = 0; i < 32; i += 8) {
        int k = kb + ty + i, n = nb + tx;
        float v = (k < d.Ksrc && n < d.Nsrc) ? d.src[(size_t)k * d.Nsrc + n] : 0.0f;
        if (d.colw && k < d.Ksrc) v *= d.colw[k];
        tile[ty + i][tx] = v;
    }
    __syncthreads();
    int u = ty * 32 + tx;                  // 0..255
    int kp = u & 15;                       // k-pair
    int nl = u >> 4;                       // 0..15
    #pragma unroll
    for (int half = 0; half < 2; ++half) {
        int n_loc = nl + 16 * half;
        int n = nb + n_loc;
        int nd = n;
        if (d.perm) {                      // kv_b: h*192+(knope 64|v 128) -> [knope 1024 | v 2048]
            int h = n / 192, dd = n - h * 192;
            nd = (dd < 64) ? h * 64 + dd : 1024 + h * 128 + (dd - 64);
        }
        bf16 lo = __float2bfloat16(tile[2 * kp][n_loc]);
        bf16 hi = __float2bfloat16(tile[2 * kp + 1][n_loc]);
        unsigned int pk = (unsigned int)*reinterpret_cast<unsigned short*>(&lo) |
                          ((unsigned int)*reinterpret_cast<unsigned short*>(&hi) << 16);
        *reinterpret_cast<unsigned int*>(d.dst + (size_t)nd * d.Kpad + kb + 2 * kp) = pk;
    }
}

// ---------------- GEMM core: C[M][N] = A[M][K] * Bt[N][K]^T  (bf16, f32 acc) --
// 128x128 tile, BK=64, 4 waves (2x2), 4x4 16x16x32 frags/wave.
// LDS [128 rows][8 chunks of 16B], phys chunk = ch ^ (row&7). gl2lds staging.
#define GEMM_VARS                                                                        \
    __shared__ bf16 As[128 * 64];                                                        \
    __shared__ bf16 Bs[128 * 64];                                                        \
    const int t = threadIdx.x;                                                           \
    const int lane = t & 63, w = t >> 6;                                                 \
    const int l15 = lane & 15, l4 = lane >> 4;                                           \
    const int wr = (w >> 1) * 64, wc = (w & 1) * 64;

#define GEMM_CORE(Aptr, Bptr, LDA, LDB, KDIM, M0V, N0V)                                  \
    const int m0 = (M0V), n0 = (N0V);                                                    \
    f32x4 acc[4][4] = {};                                                                \
    for (int k0 = 0; k0 < (KDIM); k0 += 64) {                                            \
        _Pragma("unroll")                                                                \
        for (int i = 0; i < 4; ++i) {                                                    \
            int cid = t + i * 256;                                                       \
            int row = cid >> 3;                                                          \
            int ch = (cid & 7) ^ (row & 7);                                              \
            gl2lds16((Aptr) + (size_t)(m0 + row) * (LDA) + k0 + ch * 8,                  \
                     reinterpret_cast<char*>(As) + cid * 16);                            \
            gl2lds16((Bptr) + (size_t)(n0 + row) * (LDB) + k0 + ch * 8,                  \
                     reinterpret_cast<char*>(Bs) + cid * 16);                            \
        }                                                                                \
        __syncthreads();                                                                 \
        _Pragma("unroll")                                                                \
        for (int kk = 0; kk < 2; ++kk) {                                                 \
            short8 a[4], b[4];                                                           \
            _Pragma("unroll")                                                            \
            for (int m = 0; m < 4; ++m) {                                                \
                int row = wr + m * 16 + l15;                                             \
                int ch = (kk * 4 + l4) ^ (row & 7);                                      \
                a[m] = *reinterpret_cast<const short8*>(                                 \
                    reinterpret_cast<const char*>(As) + row * 128 + ch * 16);            \
            }                                                                            \
            _Pragma("unroll")                                                            \
            for (int n = 0; n < 4; ++n) {                                                \
                int row = wc + n * 16 + l15;                                             \
                int ch = (kk * 4 + l4) ^ (row & 7);                                      \
                b[n] = *reinterpret_cast<const short8*>(                                 \
                    reinterpret_cast<const char*>(Bs) + row * 128 + ch * 16);            \
            }                                                                            \
            _Pragma("unroll")                                                            \
            for (int m = 0; m < 4; ++m)                                                  \
                _Pragma("unroll")                                                        \
                for (int n = 0; n < 4; ++n)                                              \
                    acc[m][n] = __builtin_amdgcn_mfma_f32_16x16x32_bf16(a[m], b[n],      \
                                                                       acc[m][n], 0, 0, 0); \
        }                                                                                \
        __syncthreads();                                                                 \
    }
// C/D layout: col = lane&15, row = (lane>>4)*4 + reg  [verified m89/m91]

template <typename OutT>
__launch_bounds__(256)
__global__ void gemm_bt(const bf16* __restrict__ A, const bf16* __restrict__ Bt,
                        OutT* __restrict__ C, int K, int lda, int ldb, int ldc)
{
    GEMM_VARS
    GEMM_CORE(A, Bt, lda, ldb, K, blockIdx.y * 128, blockIdx.x * 128)
    #pragma unroll
    for (int m = 0; m < 4; ++m)
        #pragma unroll
        for (int n = 0; n < 4; ++n)
            #pragma unroll
            for (int j = 0; j < 4; ++j) {
                int r = m0 + wr + m * 16 + l4 * 4 + j;
                int c = n0 + wc + n * 16 + l15;
                float v = acc[m][n][j];
                if constexpr (sizeof(OutT) == 2) C[(size_t)r * ldc + c] = __float2bfloat16(v);
                else                             C[(size_t)r * ldc + c] = v;
            }
}

// ---------------- merged up-projections (one dispatch) ------------------------
// ln weights are folded into the transposed weights; per-row rms scalars qs/ks
// are applied in the epilogues -> A operand is qac directly (no qan/ckvn).
// blockIdx.x < 16: q_b GEMM + fused RoPE/scale/scatter (N-tile == one head).
// blockIdx.x >= 16: kv_b GEMM (permuted weights) -> knope + direct V^T.
__launch_bounds__(256)
__global__ void gemm_up(const bf16* __restrict__ qac, const bf16* __restrict__ qb_wt,
                        const float* __restrict__ ct, const float* __restrict__ st,
                        const float* __restrict__ qs, bf16* __restrict__ Qf,
                        const bf16* __restrict__ kvb_wt, const float* __restrict__ ks,
                        bf16* __restrict__ knope, bf16* __restrict__ Vt)
{
    GEMM_VARS
    if (blockIdx.x < 16) {
        GEMM_CORE(qac, qb_wt, NA_, QLORA_P, QLORA_P, blockIdx.y * 128, blockIdx.x * 128)
        (void)n0;
        const int h = blockIdx.x;                  // head
        if (wc == 0) {
            #pragma unroll
            for (int m = 0; m < 4; ++m) {
                int rb = m0 + wr + m * 16 + l4 * 4;
                float q4[4];
                #pragma unroll
                for (int j = 0; j < 4; ++j) q4[j] = qs[rb + j] * SCL2_;
                #pragma unroll
                for (int n = 0; n < 4; ++n)
                    #pragma unroll
                    for (int j = 0; j < 4; ++j) {
                        int r = rb + j;
                        int c = n * 16 + l15;                   // [0,64) nope
                        int s = r & (S_ - 1), bq = r >> 11;
                        Qf[((size_t)(bq * NH_ + h) * S_ + s) * 128 + c] =
                            __float2bfloat16(acc[m][n][j] * q4[j]);
                    }
            }
        } else {
            #pragma unroll
            for (int m = 0; m < 4; ++m) {
                int rb = m0 + wr + m * 16 + l4 * 4;
                float q4[4];
                #pragma unroll
                for (int j = 0; j < 4; ++j) q4[j] = qs[rb + j] * SCL2_;
                #pragma unroll
                for (int n = 0; n < 4; ++n)
                    #pragma unroll
                    for (int j = 0; j < 4; ++j) {
                        int r = rb + j;
                        int p = n * 16 + l15;                   // pe-local [0,64)
                        int jj = p >> 1, odd = p & 1;
                        float v = acc[m][n][j];
                        float pr = __shfl_xor(v, 1);
                        float e0 = odd ? pr : v, e1 = odd ? v : pr;
                        int s = r & (S_ - 1), bq = r >> 11;
                        float c_ = ct[s * 32 + jj], s_ = st[s * 32 + jj];
                        float ov = odd ? (e1 * c_ + e0 * s_) : (e0 * c_ - e1 * s_);
                        int c_out = 64 + (odd ? 32 : 0) + jj;
                        Qf[((size_t)(bq * NH_ + h) * S_ + s) * 128 + c_out] =
                            __float2bfloat16(ov * q4[j]);
                    }
            }
        }
    } else {
        GEMM_CORE(qac + NQA_P, kvb_wt, NA_, KVLORA_, KVLORA_, blockIdx.y * 128,
                  (blockIdx.x - 16) * 128)
        if (n0 < 1024) {
            #pragma unroll
            for (int m = 0; m < 4; ++m) {
                int rb = m0 + wr + m * 16 + l4 * 4;
                float k4[4];
                #pragma unroll
                for (int j = 0; j < 4; ++j) k4[j] = ks[rb + j];
                #pragma unroll
                for (int n = 0; n < 4; ++n)
                    #pragma unroll
                    for (int j = 0; j < 4; ++j) {
                        int c = n0 + wc + n * 16 + l15;
                        knope[(size_t)(rb + j) * 1024 + c] =
                            __float2bfloat16(acc[m][n][j] * k4[j]);
                    }
            }
        } else {
            const int h = (n0 - 1024) >> 7;
            const int bq = m0 >> 11;               // uniform per block (128-row tile)
            const int bh = bq * NH_ + h;
            #pragma unroll
            for (int m = 0; m < 4; ++m) {
                int rb = m0 + wr + m * 16 + l4 * 4;
                int s = rb & (S_ - 1);
                float k4[4];
                #pragma unroll
                for (int j = 0; j < 4; ++j) k4[j] = ks[rb + j];
                #pragma unroll
                for (int n = 0; n < 4; ++n) {
                    int cl = wc + n * 16 + l15;    // d within head
                    ushort4 pk;
                    {
                        bf16 h0 = __float2bfloat16(acc[m][n][0] * k4[0]);
                        bf16 h1 = __float2bfloat16(acc[m][n][1] * k4[1]);
                        bf16 h2 = __float2bfloat16(acc[m][n][2] * k4[2]);
                        bf16 h3 = __float2bfloat16(acc[m][n][3] * k4[3]);
                        pk.x = *reinterpret_cast<unsigned short*>(&h0);
                        pk.y = *reinterpret_cast<unsigned short*>(&h1);
                        pk.z = *reinterpret_cast<unsigned short*>(&h2);
                        pk.w = *reinterpret_cast<unsigned short*>(&h3);
                    }
                    *reinterpret_cast<ushort4*>(Vt + ((size_t)bh * 128 + cl) * S_ + s) = pk;
                }
            }
        }
    }
}

// ---------------- per-row rms scalars + k_pe rope -----------------------------
__launch_bounds__(256)
__global__ void k_scales(const bf16* __restrict__ qac,
                         const float* __restrict__ ct, const float* __restrict__ st,
                         float* __restrict__ qs, float* __restrict__ ks,
                         bf16* __restrict__ kr)
{
    __shared__ float red[8];
    int bs = blockIdx.x;
    int t = threadIdx.x, lane = t & 63, w = t >> 6;
    int s = bs & (S_ - 1);
    const unsigned int* qp = reinterpret_cast<const unsigned int*>(qac + (size_t)bs * NA_);
    float sq = 0.f, sk = 0.f;
    for (int p = t; p < 341; p += 256) {                 // q_a cols 0..681 as pairs
        unsigned int u = qp[p];
        float a = bfLo(u), b = bfHi(u);
        sq += a * a + b * b;
    }
    if (t < 128) {                                       // ckv cols 768..1023 as pairs
        unsigned int u = qp[384 + t];
        float a = bfLo(u), b = bfHi(u);
        sk = a * a + b * b;
    }
    #pragma unroll
    for (int m = 1; m < 64; m <<= 1) { sq += __shfl_xor(sq, m); sk += __shfl_xor(sk, m); }
    if (lane == 0) { red[w] = sq; red[4 + w] = sk; }
    __syncthreads();
    if (t == 0) {
        sq = red[0] + red[1] + red[2] + red[3];
        sk = red[4] + red[5] + red[6] + red[7];
        qs[bs] = rsqrtf(sq / (float)QLORA_ + EPS_);
        ks[bs] = rsqrtf(sk / (float)KVLORA_ + EPS_);
    }
    if (t < 64) {                                        // k_pe rope (cols 1024..1087)
        int j = t & 31;
        float c_ = ct[s * 32 + j], s_ = st[s * 32 + j];
        unsigned int u = qp[512 + j];                    // pair (2j, 2j+1) of kpe
        float e0 = bfLo(u), e1 = bfHi(u);
        float v = (t < 32) ? (e0 * c_ - e1 * s_) : (e1 * c_ + e0 * s_);
        kr[(size_t)bs * 64 + t] = __float2bfloat16(v);
    }
}

// ---------------- causal flash attention --------------------------------------
// block = 128 q-rows x (b,h). 8 waves, each owns 16 q-rows. Q in registers
// (pre-scaled by qs*SCALE*log2e). K gathered from knope+kr; V from Vt.
// Double-buffered K/V, one barrier per tile. LDS 80 KiB -> 2 blocks/CU.
// SWAPPED QK^T: sfr = mfma(K_frag, Q_frag) puts q-row in l15, 16 k's in-lane.
// VGPR must stay ~64: bounds (512,4) (R5 lesson: tighter bound -> spills).
__launch_bounds__(512, 4)
__global__ void k_flash(const bf16* __restrict__ Qf, const bf16* __restrict__ knope,
                        const bf16* __restrict__ kr, const bf16* __restrict__ Vt,
                        bf16* __restrict__ attn_out)
{
    __shared__ bf16 Ks[2][64 * 128];      // [64 k-rows][16 chunks], swz ch^(row&7)
    __shared__ bf16 Vs[2][128 * 64];      // [128 d-rows][8 chunks]
    __shared__ bf16 Ps[8][16 * 64];       // per-wave P strip [16 q-rows][64 k], swz

    const int t = threadIdx.x, lane = t & 63, w = t >> 6;
    const int l15 = lane & 15, l4 = lane >> 4;
    // heavy-first: y=0..7 -> qb 15..8 (launched first), y=8..15 -> qb 0..7
    const int qb = (blockIdx.y < 8) ? (15 - blockIdx.y) : (blockIdx.y - 8);
    const int bh = blockIdx.x;
    const int q0 = qb * 128;
    const int b = bh >> 4, h = bh & 15;
    const int r0 = q0 + w * 16;           // wave's first q-row

    // Q -> registers (one-time strided read; L2/L3 absorbs). Pre-scaled.
    short8 qa_[4];
    {
        const bf16* qrow = Qf + ((size_t)bh * S_ + r0 + l15) * 128;
        #pragma unroll
        for (int kk = 0; kk < 4; ++kk)
            qa_[kk] = *reinterpret_cast<const short8*>(qrow + kk * 32 + l4 * 8);
    }

    // hoisted per-lane staging sources (advance by constant stride per tile)
    const bf16 *kSrc0, *kSrc1, *vSrc0, *vSrc1;
    size_t kStp0, kStp1;
    {
        int cid = t, row = cid >> 4, ch = (cid & 15) ^ (row & 7);
        kSrc0 = (ch < 8) ? knope + (size_t)(b * S_ + row) * 1024 + h * 64 + ch * 8
                         : kr + (size_t)(b * S_ + row) * 64 + (ch - 8) * 8;
        kStp0 = (ch < 8) ? (size_t)64 * 1024 : (size_t)64 * 64;
    }
    {
        int cid = t + 512, row = cid >> 4, ch = (cid & 15) ^ (row & 7);
        kSrc1 = (ch < 8) ? knope + (size_t)(b * S_ + row) * 1024 + h * 64 + ch * 8
                         : kr + (size_t)(b * S_ + row) * 64 + (ch - 8) * 8;
        kStp1 = (ch < 8) ? (size_t)64 * 1024 : (size_t)64 * 64;
    }
    {
        const bf16* Vg = Vt + (size_t)bh * 128 * S_;
        int cid = t, row = cid >> 3, ch = (cid & 7) ^ (row & 7);
        vSrc0 = Vg + (size_t)row * S_ + ch * 8;
        cid = t + 512; row = cid >> 3; ch = (cid & 7) ^ (row & 7);
        vSrc1 = Vg + (size_t)row * S_ + ch * 8;
    }
    auto stage = [&](int buf) {
        gl2lds16(kSrc0, reinterpret_cast<char*>(Ks[buf]) + t * 16);
        gl2lds16(kSrc1, reinterpret_cast<char*>(Ks[buf]) + (t + 512) * 16);
        gl2lds16(vSrc0, reinterpret_cast<char*>(Vs[buf]) + t * 16);
        gl2lds16(vSrc1, reinterpret_cast<char*>(Vs[buf]) + (t + 512) * 16);
        kSrc0 += kStp0; kSrc1 += kStp1; vSrc0 += 64; vSrc1 += 64;
    };

    const int NT = qb * 2 + 2;                     // 64-wide K tiles
    stage(0);
    __syncthreads();

    f32x4 o[8] = {};
    float m_r = -1e30f, l_r = 0.f;                 // per-lane: q-row = r0 + l15

    int cur = 0;
    for (int kb = 0; kb < NT; ++kb) {
        const int k0 = kb * 64;
        if (kb + 1 < NT) stage(cur ^ 1);           // next-tile loads fly under compute

        if (k0 <= r0 + 15) {                       // skip fully-masked tiles for this wave
            // S^T strip = K(64x128) @ Q^T(128x16): lane holds q=r0+l15,
            // k = k0 + m*16 + l4*4 + j   (log2 domain via pre-scaled Q)
            f32x4 sfr[4] = {};
            __builtin_amdgcn_s_setprio(1);
            #pragma unroll
            for (int kk = 0; kk < 4; ++kk) {
                short8 kf[4];
                #pragma unroll
                for (int m = 0; m < 4; ++m) {
                    int row = m * 16 + l15;
                    int ch = (kk * 4 + l4) ^ (row & 7);
                    kf[m] = *reinterpret_cast<const short8*>(
                        reinterpret_cast<const char*>(Ks[cur]) + row * 256 + ch * 16);
                }
                #pragma unroll
                for (int m = 0; m < 4; ++m)
                    sfr[m] = __builtin_amdgcn_mfma_f32_16x16x32_bf16(kf[m], qa_[kk], sfr[m], 0, 0, 0);
            }
            __builtin_amdgcn_s_setprio(0);

            const int qrow = r0 + l15;
            if (k0 + 63 > r0) {                    // causal mask (k > q)
                #pragma unroll
                for (int m = 0; m < 4; ++m) {
                    int kbase = k0 + m * 16 + l4 * 4;
                    #pragma unroll
                    for (int j = 0; j < 4; ++j)
                        if (kbase + j > qrow) sfr[m][j] = -1e30f;
                }
            }

            // row max: in-lane tree over 16 + 2 shfl across the l4 group
            float rm;
            {
                float a0 = fmaxf(fmaxf(sfr[0][0], sfr[0][1]), fmaxf(sfr[0][2], sfr[0][3]));
                float a1 = fmaxf(fmaxf(sfr[1][0], sfr[1][1]), fmaxf(sfr[1][2], sfr[1][3]));
                float a2 = fmaxf(fmaxf(sfr[2][0], sfr[2][1]), fmaxf(sfr[2][2], sfr[2][3]));
                float a3 = fmaxf(fmaxf(sfr[3][0], sfr[3][1]), fmaxf(sfr[3][2], sfr[3][3]));
                rm = fmaxf(fmaxf(a0, a1), fmaxf(a2, a3));
            }
            rm = fmaxf(rm, __shfl_xor(rm, 16));
            rm = fmaxf(rm, __shfl_xor(rm, 32));

            // defer-rescale (T13, THR=8 in log2 domain)
            if (__ballot(rm > m_r + 8.0f)) {
                float mn = fmaxf(m_r, rm);
                float alpha = exp2f(m_r - mn);
                m_r = mn;
                l_r *= alpha;
                float aj[4];
                #pragma unroll
                for (int j = 0; j < 4; ++j) aj[j] = __shfl(alpha, l4 * 4 + j);
                #pragma unroll
                for (int n = 0; n < 8; ++n)
                    #pragma unroll
                    for (int j = 0; j < 4; ++j) o[n][j] *= aj[j];
            }

            // P = exp2(S - m), pack pairs, one ds_write_b64 per m-frag
            char* pb = reinterpret_cast<char*>(Ps[w]);
            float rs = 0.f;
            #pragma unroll
            for (int m = 0; m < 4; ++m) {
                float p0 = exp2f(sfr[m][0] - m_r);
                float p1 = exp2f(sfr[m][1] - m_r);
                float p2 = exp2f(sfr[m][2] - m_r);
                float p3 = exp2f(sfr[m][3] - m_r);
                rs += (p0 + p1) + (p2 + p3);
                union { __hip_bfloat162 h; unsigned int u; } cl, ch2;
                cl.h  = __float22bfloat162_rn(make_float2(p0, p1));
                ch2.h = __float22bfloat162_rn(make_float2(p2, p3));
                int kloc = m * 16 + l4 * 4;
                int chnk = (kloc >> 3) ^ (l15 & 7);
                uint2 pk2; pk2.x = cl.u; pk2.y = ch2.u;
                *reinterpret_cast<uint2*>(pb + l15 * 128 + chnk * 16 + (kloc & 7) * 2) = pk2;
            }
            rs += __shfl_xor(rs, 16);
            rs += __shfl_xor(rs, 32);
            l_r += rs;

            // O += P(16x64) @ V(64x128)   (layout identical to prior rounds)
            __builtin_amdgcn_s_setprio(1);
            #pragma unroll
            for (int kk = 0; kk < 2; ++kk) {
                int pch = (kk * 4 + l4) ^ (l15 & 7);
                short8 pa = *reinterpret_cast<const short8*>(pb + l15 * 128 + pch * 16);
                #pragma unroll
                for (int n = 0; n < 8; ++n) {
                    int row = n * 16 + l15;
                    int ch = (kk * 4 + l4) ^ (row & 7);
                    short8 vb = *reinterpret_cast<const short8*>(
                        reinterpret_cast<const char*>(Vs[cur]) + row * 128 + ch * 16);
                    o[n] = __builtin_amdgcn_mfma_f32_16x16x32_bf16(pa, vb, o[n], 0, 0, 0);
                }
            }
            __builtin_amdgcn_s_setprio(0);
        }
        __syncthreads();     // drains next-tile loads (they flew under compute) + syncs
        cur ^= 1;
    }

    // l_r lives at lane with l15 == q-local; o[n][j] is q-local = l4*4+j
    float rj[4];
    #pragma unroll
    for (int j = 0; j < 4; ++j) rj[j] = __builtin_amdgcn_rcpf(__shfl(l_r, l4 * 4 + j));
    size_t obase = ((size_t)(b * S_) + q0 + w * 16) * (size_t)(NH_ * VDIM_) + h * VDIM_;
    #pragma unroll
    for (int n = 0; n < 8; ++n)
        #pragma unroll
        for (int j = 0; j < 4; ++j) {
            int r = l4 * 4 + j;
            int c = n * 16 + l15;
            attn_out[obase + (size_t)r * (NH_ * VDIM_) + c] = __float2bfloat16(o[n][j] * rj[j]);
        }
}

// ==============================================================================
extern "C" void kernel_launch(void* const* d_in, const int* in_sizes, int n_in,
                              void* d_out, int out_size, void* d_ws, size_t ws_size,
                              hipStream_t stream)
{
    (void)in_sizes; (void)n_in; (void)out_size;
    const float* x       = (const float*)d_in[0];
    const float* q_a_w   = (const float*)d_in[1];
    const float* q_a_ln  = (const float*)d_in[2];
    const float* q_b_w   = (const float*)d_in[3];
    const float* kv_a_w  = (const float*)d_in[4];
    const float* kv_a_ln = (const float*)d_in[5];
    const float* kv_b_w  = (const float*)d_in[6];
    const float* o_w     = (const float*)d_in[7];
    float* out = (float*)d_out;

    char* ws = (char*)d_ws;
    size_t off = 0;
    auto alloc = [&](size_t bytes) -> char* {
        char* p = ws + off;
        off += (bytes + 255) & ~(size_t)255;
        return p;
    };

    bf16* xb     = (bf16*)alloc((size_t)BS_ * HID_ * 2);        // reused as Qf after gemm_a
    bf16* a_wt   = (bf16*)alloc((size_t)NA_ * HID_ * 2);        // merged [q_a | kv_a]^T
    bf16* qb_wt  = (bf16*)alloc((size_t)2048 * QLORA_P * 2);    // qln folded
    bf16* kvb_wt = (bf16*)alloc((size_t)3072 * KVLORA_ * 2);    // permuted cols, kvln folded
    bf16* ow_t   = (bf16*)alloc((size_t)2048 * 2048 * 2);
    float* ct    = (float*)alloc((size_t)S_ * 32 * 4);
    float* st    = (float*)alloc((size_t)S_ * 32 * 4);
    bf16* qac    = (bf16*)alloc((size_t)BS_ * NA_ * 2);         // down-proj out [qa|ckvkpe]
    float* qs    = (float*)alloc((size_t)BS_ * 4);              // per-row rms scalars
    float* ksc   = (float*)alloc((size_t)BS_ * 4);
    bf16* kr     = (bf16*)alloc((size_t)BS_ * 64 * 2);
    bf16* knope  = (bf16*)alloc((size_t)BS_ * 1024 * 2);
    bf16* Vt     = (bf16*)alloc((size_t)BS_ * 2048 * 2);        // [bh][128][S]
    bf16* attn   = (bf16*)alloc((size_t)BS_ * 2048 * 2);

    bf16* Qf = xb;   // xb dead after gemm_a

    if (ws_size < off) return;  // diagnostic guard: absmax would stay exactly 3.468750

    // stage 0: merged prep (weight transposes + ln-fold + x convert + rope tables)
    TDs P;
    //              src      dst                   colw     Ksrc  Nsrc  Kpad  tX  off   perm
    P.d[0] = TD{ q_a_w,  a_wt,                     nullptr, 2048,  682, 2048, 64,    0, 0 };
    P.d[1] = TD{ kv_a_w, a_wt + (size_t)NQA_P*2048,nullptr, 2048,  320, 2048, 64, 1536, 0 };
    P.d[2] = TD{ q_b_w,  qb_wt,                    q_a_ln,   682, 2048,  704, 22, 2304, 0 };
    P.d[3] = TD{ kv_b_w, kvb_wt,                   kv_a_ln,  256, 3072,  256,  8, 3712, 1 };
    P.d[4] = TD{ o_w,    ow_t,                     nullptr, 2048, 2048, 2048, 64, 4480, 0 };
    k_prep<<<PREP_TILES + 8192 + 256, dim3(32, 8), 0, stream>>>(P, x, xb, ct, st);

    // stage 1: merged down-projection  qac = x @ [q_a|kv_a]
    gemm_bt<bf16><<<dim3(NA_ / 128, BS_ / 128), 256, 0, stream>>>(xb, a_wt, qac,
                                                                  HID_, HID_, HID_, NA_);

    // stage 2: per-row rms scalars + k_pe rope
    k_scales<<<BS_, 256, 0, stream>>>(qac, ct, st, qs, ksc, kr);

    // stage 3: merged up-projections with fused epilogues (one dispatch)
    gemm_up<<<dim3(16 + 24, BS_ / 128), 256, 0, stream>>>(qac, qb_wt, ct, st, qs, Qf,
                                                          kvb_wt, ksc, knope, Vt);

    // stage 4: causal flash attention (heavy-first qb order, dbuf K/V, swapped QK)
    k_flash<<<dim3(B_ * NH_, S_ / 128), 512, 0, stream>>>(Qf, knope, kr, Vt, attn);

    // stage 5: output projection (f32 out)
    gemm_bt<float><<<dim3(2048 / 128, BS_ / 128), 256, 0, stream>>>(attn, ow_t, out,
                                                                    HID_, HID_, HID_, 2048);
}

// Round 9
// 219.965 us; speedup vs baseline: 2.0955x; 1.0248x over previous
//
#include <hip/hip_runtime.h>
#include <hip/hip_bf16.h>

typedef __attribute__((ext_vector_type(8))) short short8;   // 8 x bf16 (MFMA A/B frag)
typedef __attribute__((ext_vector_type(4))) float f32x4;    // MFMA C/D frag

using bf16 = __hip_bfloat16;

static constexpr int B_ = 2, S_ = 2048, HID_ = 2048, NH_ = 16;
static constexpr int ROPE_ = 64, VDIM_ = 128, QHEAD_ = 128;
static constexpr int QLORA_ = 682, KVLORA_ = 256;
static constexpr int QLORA_P = 704;   // K padded to mult of 64
static constexpr int NQA_P = 768;     // q_a N padded
static constexpr int NKVA_P = 384;    // kv_a N padded
static constexpr int NA_ = NQA_P + NKVA_P;   // 1152 merged down-proj N
static constexpr float THETA_ = 128000.0f;
static constexpr float SCALE_ = 0.08838834764831845f;  // 1/sqrt(128)
static constexpr float SCL2_ = 0.08838834764831845f * 1.4426950408889634f; // fold log2e
static constexpr float EPS_ = 1e-6f;
static constexpr int BS_ = B_ * S_;   // 4096

// async global->LDS, 16B per lane. Dest must be linear in lane order
// (wave-uniform base + lane*16); source is per-lane (may be swizzled/gathered).
__device__ __forceinline__ void gl2lds16(const void* g, void* l) {
    __builtin_amdgcn_global_load_lds(
        (const __attribute__((address_space(1))) unsigned int*)g,
        (__attribute__((address_space(3))) unsigned int*)l, 16, 0, 0);
}

struct bf16x4_s { bf16 x, y, z, w; };

__device__ __forceinline__ float bfLo(unsigned int u) { return __uint_as_float(u << 16); }
__device__ __forceinline__ float bfHi(unsigned int u) { return __uint_as_float(u & 0xffff0000u); }

// ---------------- merged prep: weight transposes + x convert + rope table -----
// colw != null: fold per-K column weight (rmsnorm ln weight) into the transposed
// matrix. Writes packed as uint (2 bf16) for 2x store coalescing.
struct TD { const float* src; bf16* dst; const float* colw;
            int Ksrc, Nsrc, Kpad, tilesX, off, perm; };
struct TDs { TD d[5]; };
static constexpr int PREP_TILES = 8576;          // transpose tile-blocks

__global__ void k_prep(TDs P, const float* __restrict__ x, bf16* __restrict__ xb,
                       float* __restrict__ ct, float* __restrict__ st) {
    __shared__ float tile[32][33];
    if (blockIdx.x >= PREP_TILES) {              // misc path
        int bid = blockIdx.x - PREP_TILES;
        int t = threadIdx.y * 32 + threadIdx.x;
        if (bid < 8192) {                        // convert BS*HID f32 -> bf16, 4/thread
            int i = bid * 256 + t;
            float4 v = reinterpret_cast<const float4*>(x)[i];
            bf16x4_s o;
            o.x = __float2bfloat16(v.x); o.y = __float2bfloat16(v.y);
            o.z = __float2bfloat16(v.z); o.w = __float2bfloat16(v.w);
            reinterpret_cast<bf16x4_s*>(xb)[i] = o;
        } else {                                 // rope table [S][32]
            int idx = (bid - 8192) * 256 + t;    // S*32 = 65536
            int tpos = idx >> 5, j = idx & 31;
            float inv = expf(-(float)j * (logf(THETA_) / 32.0f));
            float f = (float)tpos * inv;
            ct[idx] = cosf(f);
            st[idx] = sinf(f);
        }
        return;
    }
    int flat = blockIdx.x;
    int di = 0;
    #pragma unroll
    for (int i = 1; i < 5; ++i) if (flat >= P.d[i].off) di = i;
    TD d = P.d[di];
    int local = flat - d.off;
    int xt = local % d.tilesX, yt = local / d.tilesX;
    int kb = xt * 32, nb = yt * 32;
    int tx = threadIdx.x, ty = threadIdx.y;          // 32 x 8
    #pragma unroll
    for (int i = 0; i < 32; i += 8) {
        int k = kb + ty + i, n = nb + tx;
        float v = (k < d.Ksrc && n < d.Nsrc) ? d.src[(size_t)k * d.Nsrc + n] : 0.0f;
        if (d.colw && k < d.Ksrc) v *= d.colw[k];
        tile[ty + i][tx] = v;
    }
    __syncthreads();
    int u = ty * 32 + tx;                  // 0..255
    int kp = u & 15;                       // k-pair
    int nl = u >> 4;                       // 0..15
    #pragma unroll
    for (int half = 0; half < 2; ++half) {
        int n_loc = nl + 16 * half;
        int n = nb + n_loc;
        int nd = n;
        if (d.perm) {                      // kv_b: h*192+(knope 64|v 128) -> [knope 1024 | v 2048]
            int h = n / 192, dd = n - h * 192;
            nd = (dd < 64) ? h * 64 + dd : 1024 + h * 128 + (dd - 64);
        }
        bf16 lo = __float2bfloat16(tile[2 * kp][n_loc]);
        bf16 hi = __float2bfloat16(tile[2 * kp + 1][n_loc]);
        unsigned int pk = (unsigned int)*reinterpret_cast<unsigned short*>(&lo) |
                          ((unsigned int)*reinterpret_cast<unsigned short*>(&hi) << 16);
        *reinterpret_cast<unsigned int*>(d.dst + (size_t)nd * d.Kpad + kb + 2 * kp) = pk;
    }
}

// ---------------- GEMM core: C[M][N] = A[M][K] * Bt[N][K]^T  (bf16, f32 acc) --
// 128x128 tile, BK=64, 4 waves (2x2), 4x4 16x16x32 frags/wave.
// LDS [128 rows][8 chunks of 16B], phys chunk = ch ^ (row&7). gl2lds staging.
#define GEMM_VARS                                                                        \
    __shared__ bf16 As[128 * 64];                                                        \
    __shared__ bf16 Bs[128 * 64];                                                        \
    const int t = threadIdx.x;                                                           \
    const int lane = t & 63, w = t >> 6;                                                 \
    const int l15 = lane & 15, l4 = lane >> 4;                                           \
    const int wr = (w >> 1) * 64, wc = (w & 1) * 64;

#define GEMM_CORE(Aptr, Bptr, LDA, LDB, KDIM, M0V, N0V)                                  \
    const int m0 = (M0V), n0 = (N0V);                                                    \
    f32x4 acc[4][4] = {};                                                                \
    for (int k0 = 0; k0 < (KDIM); k0 += 64) {                                            \
        _Pragma("unroll")                                                                \
        for (int i = 0; i < 4; ++i) {                                                    \
            int cid = t + i * 256;                                                       \
            int row = cid >> 3;                                                          \
            int ch = (cid & 7) ^ (row & 7);                                              \
            gl2lds16((Aptr) + (size_t)(m0 + row) * (LDA) + k0 + ch * 8,                  \
                     reinterpret_cast<char*>(As) + cid * 16);                            \
            gl2lds16((Bptr) + (size_t)(n0 + row) * (LDB) + k0 + ch * 8,                  \
                     reinterpret_cast<char*>(Bs) + cid * 16);                            \
        }                                                                                \
        __syncthreads();                                                                 \
        _Pragma("unroll")                                                                \
        for (int kk = 0; kk < 2; ++kk) {                                                 \
            short8 a[4], b[4];                                                           \
            _Pragma("unroll")                                                            \
            for (int m = 0; m < 4; ++m) {                                                \
                int row = wr + m * 16 + l15;                                             \
                int ch = (kk * 4 + l4) ^ (row & 7);                                      \
                a[m] = *reinterpret_cast<const short8*>(                                 \
                    reinterpret_cast<const char*>(As) + row * 128 + ch * 16);            \
            }                                                                            \
            _Pragma("unroll")                                                            \
            for (int n = 0; n < 4; ++n) {                                                \
                int row = wc + n * 16 + l15;                                             \
                int ch = (kk * 4 + l4) ^ (row & 7);                                      \
                b[n] = *reinterpret_cast<const short8*>(                                 \
                    reinterpret_cast<const char*>(Bs) + row * 128 + ch * 16);            \
            }                                                                            \
            _Pragma("unroll")                                                            \
            for (int m = 0; m < 4; ++m)                                                  \
                _Pragma("unroll")                                                        \
                for (int n = 0; n < 4; ++n)                                              \
                    acc[m][n] = __builtin_amdgcn_mfma_f32_16x16x32_bf16(a[m], b[n],      \
                                                                       acc[m][n], 0, 0, 0); \
        }                                                                                \
        __syncthreads();                                                                 \
    }
// C/D layout: col = lane&15, row = (lane>>4)*4 + reg  [verified m89/m91]

template <typename OutT>
__launch_bounds__(256)
__global__ void gemm_bt(const bf16* __restrict__ A, const bf16* __restrict__ Bt,
                        OutT* __restrict__ C, int K, int lda, int ldb, int ldc)
{
    GEMM_VARS
    GEMM_CORE(A, Bt, lda, ldb, K, blockIdx.y * 128, blockIdx.x * 128)
    #pragma unroll
    for (int m = 0; m < 4; ++m)
        #pragma unroll
        for (int n = 0; n < 4; ++n)
            #pragma unroll
            for (int j = 0; j < 4; ++j) {
                int r = m0 + wr + m * 16 + l4 * 4 + j;
                int c = n0 + wc + n * 16 + l15;
                float v = acc[m][n][j];
                if constexpr (sizeof(OutT) == 2) C[(size_t)r * ldc + c] = __float2bfloat16(v);
                else                             C[(size_t)r * ldc + c] = v;
            }
}

// ---------------- merged up-projections (one dispatch) ------------------------
// ln weights are folded into the transposed weights; per-row rms scalars qs/ks
// are applied in the epilogues -> A operand is qac directly (no qan/ckvn).
// blockIdx.x < 16: q_b GEMM + fused RoPE/scale/scatter (N-tile == one head).
// blockIdx.x >= 16: kv_b GEMM (permuted weights) -> knope + direct V^T.
__launch_bounds__(256)
__global__ void gemm_up(const bf16* __restrict__ qac, const bf16* __restrict__ qb_wt,
                        const float* __restrict__ ct, const float* __restrict__ st,
                        const float* __restrict__ qs, bf16* __restrict__ Qf,
                        const bf16* __restrict__ kvb_wt, const float* __restrict__ ks,
                        bf16* __restrict__ knope, bf16* __restrict__ Vt)
{
    GEMM_VARS
    if (blockIdx.x < 16) {
        GEMM_CORE(qac, qb_wt, NA_, QLORA_P, QLORA_P, blockIdx.y * 128, blockIdx.x * 128)
        (void)n0;
        const int h = blockIdx.x;                  // head
        if (wc == 0) {
            #pragma unroll
            for (int m = 0; m < 4; ++m) {
                int rb = m0 + wr + m * 16 + l4 * 4;
                float q4[4];
                #pragma unroll
                for (int j = 0; j < 4; ++j) q4[j] = qs[rb + j] * SCL2_;
                #pragma unroll
                for (int n = 0; n < 4; ++n)
                    #pragma unroll
                    for (int j = 0; j < 4; ++j) {
                        int r = rb + j;
                        int c = n * 16 + l15;                   // [0,64) nope
                        int s = r & (S_ - 1), bq = r >> 11;
                        Qf[((size_t)(bq * NH_ + h) * S_ + s) * 128 + c] =
                            __float2bfloat16(acc[m][n][j] * q4[j]);
                    }
            }
        } else {
            #pragma unroll
            for (int m = 0; m < 4; ++m) {
                int rb = m0 + wr + m * 16 + l4 * 4;
                float q4[4];
                #pragma unroll
                for (int j = 0; j < 4; ++j) q4[j] = qs[rb + j] * SCL2_;
                #pragma unroll
                for (int n = 0; n < 4; ++n)
                    #pragma unroll
                    for (int j = 0; j < 4; ++j) {
                        int r = rb + j;
                        int p = n * 16 + l15;                   // pe-local [0,64)
                        int jj = p >> 1, odd = p & 1;
                        float v = acc[m][n][j];
                        float pr = __shfl_xor(v, 1);
                        float e0 = odd ? pr : v, e1 = odd ? v : pr;
                        int s = r & (S_ - 1), bq = r >> 11;
                        float c_ = ct[s * 32 + jj], s_ = st[s * 32 + jj];
                        float ov = odd ? (e1 * c_ + e0 * s_) : (e0 * c_ - e1 * s_);
                        int c_out = 64 + (odd ? 32 : 0) + jj;
                        Qf[((size_t)(bq * NH_ + h) * S_ + s) * 128 + c_out] =
                            __float2bfloat16(ov * q4[j]);
                    }
            }
        }
    } else {
        GEMM_CORE(qac + NQA_P, kvb_wt, NA_, KVLORA_, KVLORA_, blockIdx.y * 128,
                  (blockIdx.x - 16) * 128)
        if (n0 < 1024) {
            #pragma unroll
            for (int m = 0; m < 4; ++m) {
                int rb = m0 + wr + m * 16 + l4 * 4;
                float k4[4];
                #pragma unroll
                for (int j = 0; j < 4; ++j) k4[j] = ks[rb + j];
                #pragma unroll
                for (int n = 0; n < 4; ++n)
                    #pragma unroll
                    for (int j = 0; j < 4; ++j) {
                        int c = n0 + wc + n * 16 + l15;
                        knope[(size_t)(rb + j) * 1024 + c] =
                            __float2bfloat16(acc[m][n][j] * k4[j]);
                    }
            }
        } else {
            const int h = (n0 - 1024) >> 7;
            const int bq = m0 >> 11;               // uniform per block (128-row tile)
            const int bh = bq * NH_ + h;
            #pragma unroll
            for (int m = 0; m < 4; ++m) {
                int rb = m0 + wr + m * 16 + l4 * 4;
                int s = rb & (S_ - 1);
                float k4[4];
                #pragma unroll
                for (int j = 0; j < 4; ++j) k4[j] = ks[rb + j];
                #pragma unroll
                for (int n = 0; n < 4; ++n) {
                    int cl = wc + n * 16 + l15;    // d within head
                    ushort4 pk;
                    {
                        bf16 h0 = __float2bfloat16(acc[m][n][0] * k4[0]);
                        bf16 h1 = __float2bfloat16(acc[m][n][1] * k4[1]);
                        bf16 h2 = __float2bfloat16(acc[m][n][2] * k4[2]);
                        bf16 h3 = __float2bfloat16(acc[m][n][3] * k4[3]);
                        pk.x = *reinterpret_cast<unsigned short*>(&h0);
                        pk.y = *reinterpret_cast<unsigned short*>(&h1);
                        pk.z = *reinterpret_cast<unsigned short*>(&h2);
                        pk.w = *reinterpret_cast<unsigned short*>(&h3);
                    }
                    *reinterpret_cast<ushort4*>(Vt + ((size_t)bh * 128 + cl) * S_ + s) = pk;
                }
            }
        }
    }
}

// ---------------- per-row rms scalars + k_pe rope -----------------------------
__launch_bounds__(256)
__global__ void k_scales(const bf16* __restrict__ qac,
                         const float* __restrict__ ct, const float* __restrict__ st,
                         float* __restrict__ qs, float* __restrict__ ks,
                         bf16* __restrict__ kr)
{
    __shared__ float red[8];
    int bs = blockIdx.x;
    int t = threadIdx.x, lane = t & 63, w = t >> 6;
    int s = bs & (S_ - 1);
    const unsigned int* qp = reinterpret_cast<const unsigned int*>(qac + (size_t)bs * NA_);
    float sq = 0.f, sk = 0.f;
    for (int p = t; p < 341; p += 256) {                 // q_a cols 0..681 as pairs
        unsigned int u = qp[p];
        float a = bfLo(u), b = bfHi(u);
        sq += a * a + b * b;
    }
    if (t < 128) {                                       // ckv cols 768..1023 as pairs
        unsigned int u = qp[384 + t];
        float a = bfLo(u), b = bfHi(u);
        sk = a * a + b * b;
    }
    #pragma unroll
    for (int m = 1; m < 64; m <<= 1) { sq += __shfl_xor(sq, m); sk += __shfl_xor(sk, m); }
    if (lane == 0) { red[w] = sq; red[4 + w] = sk; }
    __syncthreads();
    if (t == 0) {
        sq = red[0] + red[1] + red[2] + red[3];
        sk = red[4] + red[5] + red[6] + red[7];
        qs[bs] = rsqrtf(sq / (float)QLORA_ + EPS_);
        ks[bs] = rsqrtf(sk / (float)KVLORA_ + EPS_);
    }
    if (t < 64) {                                        // k_pe rope (cols 1024..1087)
        int j = t & 31;
        float c_ = ct[s * 32 + j], s_ = st[s * 32 + j];
        unsigned int u = qp[512 + j];                    // pair (2j, 2j+1) of kpe
        float e0 = bfLo(u), e1 = bfHi(u);
        float v = (t < 32) ? (e0 * c_ - e1 * s_) : (e1 * c_ + e0 * s_);
        kr[(size_t)bs * 64 + t] = __float2bfloat16(v);
    }
}

// ---------------- causal flash attention (balanced pairs) ---------------------
// block = (b,h) x pair i: TWO 64-row q-strips {i, 31-i} sharing the staged K/V.
// Waves 0-3 own strip 31-i (late), waves 4-7 own strip i (early). Per-block
// compute = 8(i+1) + 4(31-2i) = 132 wave-tiles, CONSTANT for all 512 blocks ->
// no straggler blocks (R8: heavy 256 vs light 16..128 wave-tiles).
// Q in registers (pre-scaled by qs*SCALE*log2e). K gathered from knope+kr;
// V from Vt. Double-buffered K/V, one barrier per tile. LDS 80 KiB -> 2/CU.
// SWAPPED QK^T: sfr = mfma(K_frag, Q_frag) puts q-row in l15, 16 k's in-lane.
// VGPR must stay ~64: bounds (512,4) (R5 lesson: tighter bound -> spills).
__launch_bounds__(512, 4)
__global__ void k_flash(const bf16* __restrict__ Qf, const bf16* __restrict__ knope,
                        const bf16* __restrict__ kr, const bf16* __restrict__ Vt,
                        bf16* __restrict__ attn_out)
{
    __shared__ bf16 Ks[2][64 * 128];      // [64 k-rows][16 chunks], swz ch^(row&7)
    __shared__ bf16 Vs[2][128 * 64];      // [128 d-rows][8 chunks]
    __shared__ bf16 Ps[8][16 * 64];       // per-wave P strip [16 q-rows][64 k], swz

    const int t = threadIdx.x, lane = t & 63, w = t >> 6;
    const int l15 = lane & 15, l4 = lane >> 4;
    const int pi = blockIdx.y;            // pair id 0..15
    const int bh = blockIdx.x;
    const int b = bh >> 4, h = bh & 15;
    // wave's strip: w<4 -> late strip (31-pi), w>=4 -> early strip (pi)
    const int strip = (w < 4) ? (31 - pi) : pi;
    const int r0 = strip * 64 + (w & 3) * 16;      // wave's first q-row
    const int NT = 32 - pi;                        // staged 64-wide K tiles

    // Q -> registers (one-time strided read; L2/L3 absorbs). Pre-scaled.
    short8 qa_[4];
    {
        const bf16* qrow = Qf + ((size_t)bh * S_ + r0 + l15) * 128;
        #pragma unroll
        for (int kk = 0; kk < 4; ++kk)
            qa_[kk] = *reinterpret_cast<const short8*>(qrow + kk * 32 + l4 * 8);
    }

    // hoisted per-lane staging sources (advance by constant stride per tile)
    const bf16 *kSrc0, *kSrc1, *vSrc0, *vSrc1;
    size_t kStp0, kStp1;
    {
        int cid = t, row = cid >> 4, ch = (cid & 15) ^ (row & 7);
        kSrc0 = (ch < 8) ? knope + (size_t)(b * S_ + row) * 1024 + h * 64 + ch * 8
                         : kr + (size_t)(b * S_ + row) * 64 + (ch - 8) * 8;
        kStp0 = (ch < 8) ? (size_t)64 * 1024 : (size_t)64 * 64;
    }
    {
        int cid = t + 512, row = cid >> 4, ch = (cid & 15) ^ (row & 7);
        kSrc1 = (ch < 8) ? knope + (size_t)(b * S_ + row) * 1024 + h * 64 + ch * 8
                         : kr + (size_t)(b * S_ + row) * 64 + (ch - 8) * 8;
        kStp1 = (ch < 8) ? (size_t)64 * 1024 : (size_t)64 * 64;
    }
    {
        const bf16* Vg = Vt + (size_t)bh * 128 * S_;
        int cid = t, row = cid >> 3, ch = (cid & 7) ^ (row & 7);
        vSrc0 = Vg + (size_t)row * S_ + ch * 8;
        cid = t + 512; row = cid >> 3; ch = (cid & 7) ^ (row & 7);
        vSrc1 = Vg + (size_t)row * S_ + ch * 8;
    }
    auto stage = [&](int buf) {
        gl2lds16(kSrc0, reinterpret_cast<char*>(Ks[buf]) + t * 16);
        gl2lds16(kSrc1, reinterpret_cast<char*>(Ks[buf]) + (t + 512) * 16);
        gl2lds16(vSrc0, reinterpret_cast<char*>(Vs[buf]) + t * 16);
        gl2lds16(vSrc1, reinterpret_cast<char*>(Vs[buf]) + (t + 512) * 16);
        kSrc0 += kStp0; kSrc1 += kStp1; vSrc0 += 64; vSrc1 += 64;
    };

    stage(0);
    __syncthreads();

    f32x4 o[8] = {};
    float m_r = -1e30f, l_r = 0.f;                 // per-lane: q-row = r0 + l15

    int cur = 0;
    for (int kb = 0; kb < NT; ++kb) {
        const int k0 = kb * 64;
        if (kb + 1 < NT) stage(cur ^ 1);           // next-tile loads fly under compute

        if (k0 <= r0 + 15) {                       // skip fully-masked tiles for this wave
            // S^T strip = K(64x128) @ Q^T(128x16): lane holds q=r0+l15,
            // k = k0 + m*16 + l4*4 + j   (log2 domain via pre-scaled Q)
            f32x4 sfr[4] = {};
            __builtin_amdgcn_s_setprio(1);
            #pragma unroll
            for (int kk = 0; kk < 4; ++kk) {
                short8 kf[4];
                #pragma unroll
                for (int m = 0; m < 4; ++m) {
                    int row = m * 16 + l15;
                    int ch = (kk * 4 + l4) ^ (row & 7);
                    kf[m] = *reinterpret_cast<const short8*>(
                        reinterpret_cast<const char*>(Ks[cur]) + row * 256 + ch * 16);
                }
                #pragma unroll
                for (int m = 0; m < 4; ++m)
                    sfr[m] = __builtin_amdgcn_mfma_f32_16x16x32_bf16(kf[m], qa_[kk], sfr[m], 0, 0, 0);
            }
            __builtin_amdgcn_s_setprio(0);

            const int qrow = r0 + l15;
            if (k0 + 63 > r0) {                    // causal mask (k > q)
                #pragma unroll
                for (int m = 0; m < 4; ++m) {
                    int kbase = k0 + m * 16 + l4 * 4;
                    #pragma unroll
                    for (int j = 0; j < 4; ++j)
                        if (kbase + j > qrow) sfr[m][j] = -1e30f;
                }
            }

            // row max: in-lane tree over 16 + 2 shfl across the l4 group
            float rm;
            {
                float a0 = fmaxf(fmaxf(sfr[0][0], sfr[0][1]), fmaxf(sfr[0][2], sfr[0][3]));
                float a1 = fmaxf(fmaxf(sfr[1][0], sfr[1][1]), fmaxf(sfr[1][2], sfr[1][3]));
                float a2 = fmaxf(fmaxf(sfr[2][0], sfr[2][1]), fmaxf(sfr[2][2], sfr[2][3]));
                float a3 = fmaxf(fmaxf(sfr[3][0], sfr[3][1]), fmaxf(sfr[3][2], sfr[3][3]));
                rm = fmaxf(fmaxf(a0, a1), fmaxf(a2, a3));
            }
            rm = fmaxf(rm, __shfl_xor(rm, 16));
            rm = fmaxf(rm, __shfl_xor(rm, 32));

            // defer-rescale (T13, THR=8 in log2 domain)
            if (__ballot(rm > m_r + 8.0f)) {
                float mn = fmaxf(m_r, rm);
                float alpha = exp2f(m_r - mn);
                m_r = mn;
                l_r *= alpha;
                float aj[4];
                #pragma unroll
                for (int j = 0; j < 4; ++j) aj[j] = __shfl(alpha, l4 * 4 + j);
                #pragma unroll
                for (int n = 0; n < 8; ++n)
                    #pragma unroll
                    for (int j = 0; j < 4; ++j) o[n][j] *= aj[j];
            }

            // P = exp2(S - m), pack pairs, one ds_write_b64 per m-frag
            char* pb = reinterpret_cast<char*>(Ps[w]);
            float rs = 0.f;
            #pragma unroll
            for (int m = 0; m < 4; ++m) {
                float p0 = exp2f(sfr[m][0] - m_r);
                float p1 = exp2f(sfr[m][1] - m_r);
                float p2 = exp2f(sfr[m][2] - m_r);
                float p3 = exp2f(sfr[m][3] - m_r);
                rs += (p0 + p1) + (p2 + p3);
                union { __hip_bfloat162 h; unsigned int u; } cl, ch2;
                cl.h  = __float22bfloat162_rn(make_float2(p0, p1));
                ch2.h = __float22bfloat162_rn(make_float2(p2, p3));
                int kloc = m * 16 + l4 * 4;
                int chnk = (kloc >> 3) ^ (l15 & 7);
                uint2 pk2; pk2.x = cl.u; pk2.y = ch2.u;
                *reinterpret_cast<uint2*>(pb + l15 * 128 + chnk * 16 + (kloc & 7) * 2) = pk2;
            }
            rs += __shfl_xor(rs, 16);
            rs += __shfl_xor(rs, 32);
            l_r += rs;

            // O += P(16x64) @ V(64x128)   (layout identical to prior rounds)
            __builtin_amdgcn_s_setprio(1);
            #pragma unroll
            for (int kk = 0; kk < 2; ++kk) {
                int pch = (kk * 4 + l4) ^ (l15 & 7);
                short8 pa = *reinterpret_cast<const short8*>(pb + l15 * 128 + pch * 16);
                #pragma unroll
                for (int n = 0; n < 8; ++n) {
                    int row = n * 16 + l15;
                    int ch = (kk * 4 + l4) ^ (row & 7);
                    short8 vb = *reinterpret_cast<const short8*>(
                        reinterpret_cast<const char*>(Vs[cur]) + row * 128 + ch * 16);
                    o[n] = __builtin_amdgcn_mfma_f32_16x16x32_bf16(pa, vb, o[n], 0, 0, 0);
                }
            }
            __builtin_amdgcn_s_setprio(0);
        }
        __syncthreads();     // drains next-tile loads (they flew under compute) + syncs
        cur ^= 1;
    }

    // l_r lives at lane with l15 == q-local; o[n][j] is q-local = l4*4+j
    float rj[4];
    #pragma unroll
    for (int j = 0; j < 4; ++j) rj[j] = __builtin_amdgcn_rcpf(__shfl(l_r, l4 * 4 + j));
    size_t obase = ((size_t)(b * S_) + r0) * (size_t)(NH_ * VDIM_) + h * VDIM_;
    #pragma unroll
    for (int n = 0; n < 8; ++n)
        #pragma unroll
        for (int j = 0; j < 4; ++j) {
            int r = l4 * 4 + j;
            int c = n * 16 + l15;
            attn_out[obase + (size_t)r * (NH_ * VDIM_) + c] = __float2bfloat16(o[n][j] * rj[j]);
        }
}

// ==============================================================================
extern "C" void kernel_launch(void* const* d_in, const int* in_sizes, int n_in,
                              void* d_out, int out_size, void* d_ws, size_t ws_size,
                              hipStream_t stream)
{
    (void)in_sizes; (void)n_in; (void)out_size;
    const float* x       = (const float*)d_in[0];
    const float* q_a_w   = (const float*)d_in[1];
    const float* q_a_ln  = (const float*)d_in[2];
    const float* q_b_w   = (const float*)d_in[3];
    const float* kv_a_w  = (const float*)d_in[4];
    const float* kv_a_ln = (const float*)d_in[5];
    const float* kv_b_w  = (const float*)d_in[6];
    const float* o_w     = (const float*)d_in[7];
    float* out = (float*)d_out;

    char* ws = (char*)d_ws;
    size_t off = 0;
    auto alloc = [&](size_t bytes) -> char* {
        char* p = ws + off;
        off += (bytes + 255) & ~(size_t)255;
        return p;
    };

    bf16* xb     = (bf16*)alloc((size_t)BS_ * HID_ * 2);        // reused as Qf after gemm_a
    bf16* a_wt   = (bf16*)alloc((size_t)NA_ * HID_ * 2);        // merged [q_a | kv_a]^T
    bf16* qb_wt  = (bf16*)alloc((size_t)2048 * QLORA_P * 2);    // qln folded
    bf16* kvb_wt = (bf16*)alloc((size_t)3072 * KVLORA_ * 2);    // permuted cols, kvln folded
    bf16* ow_t   = (bf16*)alloc((size_t)2048 * 2048 * 2);
    float* ct    = (float*)alloc((size_t)S_ * 32 * 4);
    float* st    = (float*)alloc((size_t)S_ * 32 * 4);
    bf16* qac    = (bf16*)alloc((size_t)BS_ * NA_ * 2);         // down-proj out [qa|ckvkpe]
    float* qs    = (float*)alloc((size_t)BS_ * 4);              // per-row rms scalars
    float* ksc   = (float*)alloc((size_t)BS_ * 4);
    bf16* kr     = (bf16*)alloc((size_t)BS_ * 64 * 2);
    bf16* knope  = (bf16*)alloc((size_t)BS_ * 1024 * 2);
    bf16* Vt     = (bf16*)alloc((size_t)BS_ * 2048 * 2);        // [bh][128][S]
    bf16* attn   = (bf16*)alloc((size_t)BS_ * 2048 * 2);

    bf16* Qf = xb;   // xb dead after gemm_a

    if (ws_size < off) return;  // diagnostic guard: absmax would stay exactly 3.468750

    // stage 0: merged prep (weight transposes + ln-fold + x convert + rope tables)
    TDs P;
    //              src      dst                   colw     Ksrc  Nsrc  Kpad  tX  off   perm
    P.d[0] = TD{ q_a_w,  a_wt,                     nullptr, 2048,  682, 2048, 64,    0, 0 };
    P.d[1] = TD{ kv_a_w, a_wt + (size_t)NQA_P*2048,nullptr, 2048,  320, 2048, 64, 1536, 0 };
    P.d[2] = TD{ q_b_w,  qb_wt,                    q_a_ln,   682, 2048,  704, 22, 2304, 0 };
    P.d[3] = TD{ kv_b_w, kvb_wt,                   kv_a_ln,  256, 3072,  256,  8, 3712, 1 };
    P.d[4] = TD{ o_w,    ow_t,                     nullptr, 2048, 2048, 2048, 64, 4480, 0 };
    k_prep<<<PREP_TILES + 8192 + 256, dim3(32, 8), 0, stream>>>(P, x, xb, ct, st);

    // stage 1: merged down-projection  qac = x @ [q_a|kv_a]
    gemm_bt<bf16><<<dim3(NA_ / 128, BS_ / 128), 256, 0, stream>>>(xb, a_wt, qac,
                                                                  HID_, HID_, HID_, NA_);

    // stage 2: per-row rms scalars + k_pe rope
    k_scales<<<BS_, 256, 0, stream>>>(qac, ct, st, qs, ksc, kr);

    // stage 3: merged up-projections with fused epilogues (one dispatch)
    gemm_up<<<dim3(16 + 24, BS_ / 128), 256, 0, stream>>>(qac, qb_wt, ct, st, qs, Qf,
                                                          kvb_wt, ksc, knope, Vt);

    // stage 4: causal flash attention (balanced strip-pairs, dbuf K/V, swapped QK)
    k_flash<<<dim3(B_ * NH_, 16), 512, 0, stream>>>(Qf, knope, kr, Vt, attn);

    // stage 5: output projection (f32 out)
    gemm_bt<float><<<dim3(2048 / 128, BS_ / 128), 256, 0, stream>>>(attn, ow_t, out,
                                                                    HID_, HID_, HID_, 2048);
}

// Round 10
// 216.723 us; speedup vs baseline: 2.1268x; 1.0150x over previous
//
#include <hip/hip_runtime.h>
#include <hip/hip_bf16.h>

typedef __attribute__((ext_vector_type(8))) short short8;   // 8 x bf16 (MFMA A/B frag)
typedef __attribute__((ext_vector_type(4))) float f32x4;    // MFMA C/D frag

using bf16 = __hip_bfloat16;

static constexpr int B_ = 2, S_ = 2048, HID_ = 2048, NH_ = 16;
static constexpr int ROPE_ = 64, VDIM_ = 128, QHEAD_ = 128;
static constexpr int QLORA_ = 682, KVLORA_ = 256;
static constexpr int QLORA_P = 704;   // K padded to mult of 64
static constexpr int NQA_P = 768;     // q_a N padded
static constexpr int NKVA_P = 384;    // kv_a N padded
static constexpr int NA_ = NQA_P + NKVA_P;   // 1152 merged down-proj N
static constexpr float THETA_ = 128000.0f;
static constexpr float SCALE_ = 0.08838834764831845f;  // 1/sqrt(128)
static constexpr float SCL2_ = 0.08838834764831845f * 1.4426950408889634f; // fold log2e
static constexpr float EPS_ = 1e-6f;
static constexpr int BS_ = B_ * S_;   // 4096

// async global->LDS, 16B per lane. Dest must be linear in lane order
// (wave-uniform base + lane*16); source is per-lane (may be swizzled/gathered).
__device__ __forceinline__ void gl2lds16(const void* g, void* l) {
    __builtin_amdgcn_global_load_lds(
        (const __attribute__((address_space(1))) unsigned int*)g,
        (__attribute__((address_space(3))) unsigned int*)l, 16, 0, 0);
}

struct bf16x4_s { bf16 x, y, z, w; };

__device__ __forceinline__ float bfLo(unsigned int u) { return __uint_as_float(u << 16); }
__device__ __forceinline__ float bfHi(unsigned int u) { return __uint_as_float(u & 0xffff0000u); }

// ---------------- merged prep: weight transposes + x convert + rope table -----
// colw != null: fold per-K column weight (rmsnorm ln weight) into the transposed
// matrix. Writes packed as uint (2 bf16) for 2x store coalescing.
struct TD { const float* src; bf16* dst; const float* colw;
            int Ksrc, Nsrc, Kpad, tilesX, off, perm; };
struct TDs { TD d[5]; };
static constexpr int PREP_TILES = 8576;          // transpose tile-blocks

__global__ void k_prep(TDs P, const float* __restrict__ x, bf16* __restrict__ xb,
                       float* __restrict__ ct, float* __restrict__ st,
                       float* __restrict__ sums) {
    __shared__ float tile[32][33];
    if (blockIdx.x >= PREP_TILES) {              // misc path
        int bid = blockIdx.x - PREP_TILES;
        int t = threadIdx.y * 32 + threadIdx.x;
        if (bid < 8192) {                        // convert BS*HID f32 -> bf16, 4/thread
            int i = bid * 256 + t;
            float4 v = reinterpret_cast<const float4*>(x)[i];
            bf16x4_s o;
            o.x = __float2bfloat16(v.x); o.y = __float2bfloat16(v.y);
            o.z = __float2bfloat16(v.z); o.w = __float2bfloat16(v.w);
            reinterpret_cast<bf16x4_s*>(xb)[i] = o;
        } else if (bid < 8192 + 256) {           // rope table [S][32]
            int idx = (bid - 8192) * 256 + t;    // S*32 = 65536
            int tpos = idx >> 5, j = idx & 31;
            float inv = expf(-(float)j * (logf(THETA_) / 32.0f));
            float f = (float)tpos * inv;
            ct[idx] = cosf(f);
            st[idx] = sinf(f);
        } else {                                 // zero qsum/ksum (8192 floats)
            int z = bid - (8192 + 256);          // 0..7
            reinterpret_cast<float4*>(sums)[z * 256 + t] = make_float4(0.f, 0.f, 0.f, 0.f);
        }
        return;
    }
    int flat = blockIdx.x;
    int di = 0;
    #pragma unroll
    for (int i = 1; i < 5; ++i) if (flat >= P.d[i].off) di = i;
    TD d = P.d[di];
    int local = flat - d.off;
    int xt = local % d.tilesX, yt = local / d.tilesX;
    int kb = xt * 32, nb = yt * 32;
    int tx = threadIdx.x, ty = threadIdx.y;          // 32 x 8
    #pragma unroll
    for (int i = 0; i < 32; i += 8) {
        int k = kb + ty + i, n = nb + tx;
        float v = (k < d.Ksrc && n < d.Nsrc) ? d.src[(size_t)k * d.Nsrc + n] : 0.0f;
        if (d.colw && k < d.Ksrc) v *= d.colw[k];
        tile[ty + i][tx] = v;
    }
    __syncthreads();
    int u = ty * 32 + tx;                  // 0..255
    int kp = u & 15;                       // k-pair
    int nl = u >> 4;                       // 0..15
    #pragma unroll
    for (int half = 0; half < 2; ++half) {
        int n_loc = nl + 16 * half;
        int n = nb + n_loc;
        int nd = n;
        if (d.perm) {                      // kv_b: h*192+(knope 64|v 128) -> [knope 1024 | v 2048]
            int h = n / 192, dd = n - h * 192;
            nd = (dd < 64) ? h * 64 + dd : 1024 + h * 128 + (dd - 64);
        }
        bf16 lo = __float2bfloat16(tile[2 * kp][n_loc]);
        bf16 hi = __float2bfloat16(tile[2 * kp + 1][n_loc]);
        unsigned int pk = (unsigned int)*reinterpret_cast<unsigned short*>(&lo) |
                          ((unsigned int)*reinterpret_cast<unsigned short*>(&hi) << 16);
        *reinterpret_cast<unsigned int*>(d.dst + (size_t)nd * d.Kpad + kb + 2 * kp) = pk;
    }
}

// ---------------- GEMM core: C[M][N] = A[M][K] * Bt[N][K]^T  (bf16, f32 acc) --
// 128x128 tile, BK=64, 4 waves (2x2), 4x4 16x16x32 frags/wave.
// LDS [128 rows][8 chunks of 16B], phys chunk = ch ^ (row&7). gl2lds staging.
#define GEMM_VARS                                                                        \
    __shared__ bf16 As[128 * 64];                                                        \
    __shared__ bf16 Bs[128 * 64];                                                        \
    const int t = threadIdx.x;                                                           \
    const int lane = t & 63, w = t >> 6;                                                 \
    const int l15 = lane & 15, l4 = lane >> 4;                                           \
    const int wr = (w >> 1) * 64, wc = (w & 1) * 64;

#define GEMM_CORE(Aptr, Bptr, LDA, LDB, KDIM, M0V, N0V)                                  \
    const int m0 = (M0V), n0 = (N0V);                                                    \
    f32x4 acc[4][4] = {};                                                                \
    for (int k0 = 0; k0 < (KDIM); k0 += 64) {                                            \
        _Pragma("unroll")                                                                \
        for (int i = 0; i < 4; ++i) {                                                    \
            int cid = t + i * 256;                                                       \
            int row = cid >> 3;                                                          \
            int ch = (cid & 7) ^ (row & 7);                                              \
            gl2lds16((Aptr) + (size_t)(m0 + row) * (LDA) + k0 + ch * 8,                  \
                     reinterpret_cast<char*>(As) + cid * 16);                            \
            gl2lds16((Bptr) + (size_t)(n0 + row) * (LDB) + k0 + ch * 8,                  \
                     reinterpret_cast<char*>(Bs) + cid * 16);                            \
        }                                                                                \
        __syncthreads();                                                                 \
        _Pragma("unroll")                                                                \
        for (int kk = 0; kk < 2; ++kk) {                                                 \
            short8 a[4], b[4];                                                           \
            _Pragma("unroll")                                                            \
            for (int m = 0; m < 4; ++m) {                                                \
                int row = wr + m * 16 + l15;                                             \
                int ch = (kk * 4 + l4) ^ (row & 7);                                      \
                a[m] = *reinterpret_cast<const short8*>(                                 \
                    reinterpret_cast<const char*>(As) + row * 128 + ch * 16);            \
            }                                                                            \
            _Pragma("unroll")                                                            \
            for (int n = 0; n < 4; ++n) {                                                \
                int row = wc + n * 16 + l15;                                             \
                int ch = (kk * 4 + l4) ^ (row & 7);                                      \
                b[n] = *reinterpret_cast<const short8*>(                                 \
                    reinterpret_cast<const char*>(Bs) + row * 128 + ch * 16);            \
            }                                                                            \
            _Pragma("unroll")                                                            \
            for (int m = 0; m < 4; ++m)                                                  \
                _Pragma("unroll")                                                        \
                for (int n = 0; n < 4; ++n)                                              \
                    acc[m][n] = __builtin_amdgcn_mfma_f32_16x16x32_bf16(a[m], b[n],      \
                                                                       acc[m][n], 0, 0, 0); \
        }                                                                                \
        __syncthreads();                                                                 \
    }
// C/D layout: col = lane&15, row = (lane>>4)*4 + reg  [verified m89/m91]

template <typename OutT>
__launch_bounds__(256)
__global__ void gemm_bt(const bf16* __restrict__ A, const bf16* __restrict__ Bt,
                        OutT* __restrict__ C, int K, int lda, int ldb, int ldc)
{
    GEMM_VARS
    GEMM_CORE(A, Bt, lda, ldb, K, blockIdx.y * 128, blockIdx.x * 128)
    #pragma unroll
    for (int m = 0; m < 4; ++m)
        #pragma unroll
        for (int n = 0; n < 4; ++n)
            #pragma unroll
            for (int j = 0; j < 4; ++j) {
                int r = m0 + wr + m * 16 + l4 * 4 + j;
                int c = n0 + wc + n * 16 + l15;
                float v = acc[m][n][j];
                if constexpr (sizeof(OutT) == 2) C[(size_t)r * ldc + c] = __float2bfloat16(v);
                else                             C[(size_t)r * ldc + c] = v;
            }
}

// ---------------- down-projection with fused rms-sums + kpe-rope epilogue -----
// qac = x @ [q_a|kv_a]. Epilogue: blocks n0<768 atomically accumulate per-row
// sum-of-squares into qsum; n0 in {768,896} into ksum; n0==1024 applies RoPE
// to kpe (from f32 acc) and writes kr directly (no qac write needed there).
__launch_bounds__(256)
__global__ void gemm_a(const bf16* __restrict__ A, const bf16* __restrict__ Bt,
                       bf16* __restrict__ qac,
                       const float* __restrict__ ct, const float* __restrict__ st,
                       float* __restrict__ qsum, float* __restrict__ ksum,
                       bf16* __restrict__ kr)
{
    GEMM_VARS
    GEMM_CORE(A, Bt, HID_, HID_, HID_, blockIdx.y * 128, blockIdx.x * 128)
    if (n0 < 1024) {
        #pragma unroll
        for (int m = 0; m < 4; ++m)
            #pragma unroll
            for (int n = 0; n < 4; ++n)
                #pragma unroll
                for (int j = 0; j < 4; ++j) {
                    int r = m0 + wr + m * 16 + l4 * 4 + j;
                    int c = n0 + wc + n * 16 + l15;
                    qac[(size_t)r * NA_ + c] = __float2bfloat16(acc[m][n][j]);
                }
        float* dst = (n0 < 768) ? qsum : ksum;   // zero-pad cols contribute 0
        #pragma unroll
        for (int m = 0; m < 4; ++m)
            #pragma unroll
            for (int j = 0; j < 4; ++j) {
                float v = acc[m][0][j] * acc[m][0][j] + acc[m][1][j] * acc[m][1][j]
                        + acc[m][2][j] * acc[m][2][j] + acc[m][3][j] * acc[m][3][j];
                v += __shfl_xor(v, 1); v += __shfl_xor(v, 2);
                v += __shfl_xor(v, 4); v += __shfl_xor(v, 8);
                if (l15 == 0) atomicAdd(&dst[m0 + wr + m * 16 + l4 * 4 + j], v);
            }
    } else if (wc == 0) {                        // kpe cols 1024..1087 -> rope -> kr
        #pragma unroll
        for (int m = 0; m < 4; ++m)
            #pragma unroll
            for (int n = 0; n < 4; ++n)
                #pragma unroll
                for (int j = 0; j < 4; ++j) {
                    int r = m0 + wr + m * 16 + l4 * 4 + j;
                    int p = n * 16 + l15;                    // pe-local [0,64)
                    int jj = p >> 1, odd = p & 1;
                    float v = acc[m][n][j];
                    float pr = __shfl_xor(v, 1);
                    float e0 = odd ? pr : v, e1 = odd ? v : pr;
                    int s = r & (S_ - 1);
                    float c_ = ct[s * 32 + jj], s_ = st[s * 32 + jj];
                    float ov = odd ? (e1 * c_ + e0 * s_) : (e0 * c_ - e1 * s_);
                    kr[(size_t)r * 64 + (odd ? 32 : 0) + jj] = __float2bfloat16(ov);
                }
    }
}

// ---------------- merged up-projections (one dispatch) ------------------------
// ln weights folded into transposed weights; per-row rms scalars computed
// inline from the atomically-accumulated sums (rsqrt in epilogue).
// blockIdx.x < 16: q_b GEMM + fused RoPE/scale/scatter (N-tile == one head).
// blockIdx.x >= 16: kv_b GEMM (permuted weights) -> knope + direct V^T.
__launch_bounds__(256)
__global__ void gemm_up(const bf16* __restrict__ qac, const bf16* __restrict__ qb_wt,
                        const float* __restrict__ ct, const float* __restrict__ st,
                        const float* __restrict__ qsum, bf16* __restrict__ Qf,
                        const bf16* __restrict__ kvb_wt, const float* __restrict__ ksum,
                        bf16* __restrict__ knope, bf16* __restrict__ Vt)
{
    GEMM_VARS
    if (blockIdx.x < 16) {
        GEMM_CORE(qac, qb_wt, NA_, QLORA_P, QLORA_P, blockIdx.y * 128, blockIdx.x * 128)
        (void)n0;
        const int h = blockIdx.x;                  // head
        if (wc == 0) {
            #pragma unroll
            for (int m = 0; m < 4; ++m) {
                int rb = m0 + wr + m * 16 + l4 * 4;
                float q4[4];
                #pragma unroll
                for (int j = 0; j < 4; ++j)
                    q4[j] = rsqrtf(qsum[rb + j] * (1.0f / (float)QLORA_) + EPS_) * SCL2_;
                #pragma unroll
                for (int n = 0; n < 4; ++n)
                    #pragma unroll
                    for (int j = 0; j < 4; ++j) {
                        int r = rb + j;
                        int c = n * 16 + l15;                   // [0,64) nope
                        int s = r & (S_ - 1), bq = r >> 11;
                        Qf[((size_t)(bq * NH_ + h) * S_ + s) * 128 + c] =
                            __float2bfloat16(acc[m][n][j] * q4[j]);
                    }
            }
        } else {
            #pragma unroll
            for (int m = 0; m < 4; ++m) {
                int rb = m0 + wr + m * 16 + l4 * 4;
                float q4[4];
                #pragma unroll
                for (int j = 0; j < 4; ++j)
                    q4[j] = rsqrtf(qsum[rb + j] * (1.0f / (float)QLORA_) + EPS_) * SCL2_;
                #pragma unroll
                for (int n = 0; n < 4; ++n)
                    #pragma unroll
                    for (int j = 0; j < 4; ++j) {
                        int r = rb + j;
                        int p = n * 16 + l15;                   // pe-local [0,64)
                        int jj = p >> 1, odd = p & 1;
                        float v = acc[m][n][j];
                        float pr = __shfl_xor(v, 1);
                        float e0 = odd ? pr : v, e1 = odd ? v : pr;
                        int s = r & (S_ - 1), bq = r >> 11;
                        float c_ = ct[s * 32 + jj], s_ = st[s * 32 + jj];
                        float ov = odd ? (e1 * c_ + e0 * s_) : (e0 * c_ - e1 * s_);
                        int c_out = 64 + (odd ? 32 : 0) + jj;
                        Qf[((size_t)(bq * NH_ + h) * S_ + s) * 128 + c_out] =
                            __float2bfloat16(ov * q4[j]);
                    }
            }
        }
    } else {
        GEMM_CORE(qac + NQA_P, kvb_wt, NA_, KVLORA_, KVLORA_, blockIdx.y * 128,
                  (blockIdx.x - 16) * 128)
        if (n0 < 1024) {
            #pragma unroll
            for (int m = 0; m < 4; ++m) {
                int rb = m0 + wr + m * 16 + l4 * 4;
                float k4[4];
                #pragma unroll
                for (int j = 0; j < 4; ++j)
                    k4[j] = rsqrtf(ksum[rb + j] * (1.0f / (float)KVLORA_) + EPS_);
                #pragma unroll
                for (int n = 0; n < 4; ++n)
                    #pragma unroll
                    for (int j = 0; j < 4; ++j) {
                        int c = n0 + wc + n * 16 + l15;
                        knope[(size_t)(rb + j) * 1024 + c] =
                            __float2bfloat16(acc[m][n][j] * k4[j]);
                    }
            }
        } else {
            const int h = (n0 - 1024) >> 7;
            const int bq = m0 >> 11;               // uniform per block (128-row tile)
            const int bh = bq * NH_ + h;
            #pragma unroll
            for (int m = 0; m < 4; ++m) {
                int rb = m0 + wr + m * 16 + l4 * 4;
                int s = rb & (S_ - 1);
                float k4[4];
                #pragma unroll
                for (int j = 0; j < 4; ++j)
                    k4[j] = rsqrtf(ksum[rb + j] * (1.0f / (float)KVLORA_) + EPS_);
                #pragma unroll
                for (int n = 0; n < 4; ++n) {
                    int cl = wc + n * 16 + l15;    // d within head
                    ushort4 pk;
                    {
                        bf16 h0 = __float2bfloat16(acc[m][n][0] * k4[0]);
                        bf16 h1 = __float2bfloat16(acc[m][n][1] * k4[1]);
                        bf16 h2 = __float2bfloat16(acc[m][n][2] * k4[2]);
                        bf16 h3 = __float2bfloat16(acc[m][n][3] * k4[3]);
                        pk.x = *reinterpret_cast<unsigned short*>(&h0);
                        pk.y = *reinterpret_cast<unsigned short*>(&h1);
                        pk.z = *reinterpret_cast<unsigned short*>(&h2);
                        pk.w = *reinterpret_cast<unsigned short*>(&h3);
                    }
                    *reinterpret_cast<ushort4*>(Vt + ((size_t)bh * 128 + cl) * S_ + s) = pk;
                }
            }
        }
    }
}

// ---------------- causal flash attention (balanced pairs, single-buffer) ------
// block = (b,h) x pair i: TWO 64-row q-strips {i, 31-i} sharing staged K/V.
// Waves 0-3 own strip 31-i, waves 4-7 own strip i; per-block work constant.
// SINGLE-buffered K/V: LDS 48 KiB -> 3 blocks/CU (24 waves); cross-block
// overlap (m114) hides the staging latency that dbuf hid intra-block.
// NOTE bounds stay (512,4): R5 lesson — (512,6) caps VGPR at 85 -> spills.
// SWAPPED QK^T: sfr = mfma(K_frag, Q_frag) puts q-row in l15, 16 k's in-lane.
__launch_bounds__(512, 4)
__global__ void k_flash(const bf16* __restrict__ Qf, const bf16* __restrict__ knope,
                        const bf16* __restrict__ kr, const bf16* __restrict__ Vt,
                        bf16* __restrict__ attn_out)
{
    __shared__ bf16 Ks[64 * 128];         // [64 k-rows][16 chunks], swz ch^(row&7)
    __shared__ bf16 Vs[128 * 64];         // [128 d-rows][8 chunks]
    __shared__ bf16 Ps[8][16 * 64];       // per-wave P strip [16 q-rows][64 k], swz

    const int t = threadIdx.x, lane = t & 63, w = t >> 6;
    const int l15 = lane & 15, l4 = lane >> 4;
    const int pi = blockIdx.y;            // pair id 0..15
    const int bh = blockIdx.x;
    const int b = bh >> 4, h = bh & 15;
    // wave's strip: w<4 -> late strip (31-pi), w>=4 -> early strip (pi)
    const int strip = (w < 4) ? (31 - pi) : pi;
    const int r0 = strip * 64 + (w & 3) * 16;      // wave's first q-row
    const int NT = 32 - pi;                        // staged 64-wide K tiles

    // Q -> registers (one-time strided read; L2/L3 absorbs). Pre-scaled.
    short8 qa_[4];
    {
        const bf16* qrow = Qf + ((size_t)bh * S_ + r0 + l15) * 128;
        #pragma unroll
        for (int kk = 0; kk < 4; ++kk)
            qa_[kk] = *reinterpret_cast<const short8*>(qrow + kk * 32 + l4 * 8);
    }

    // hoisted per-lane staging sources (advance by constant stride per tile)
    const bf16 *kSrc0, *kSrc1, *vSrc0, *vSrc1;
    size_t kStp0, kStp1;
    {
        int cid = t, row = cid >> 4, ch = (cid & 15) ^ (row & 7);
        kSrc0 = (ch < 8) ? knope + (size_t)(b * S_ + row) * 1024 + h * 64 + ch * 8
                         : kr + (size_t)(b * S_ + row) * 64 + (ch - 8) * 8;
        kStp0 = (ch < 8) ? (size_t)64 * 1024 : (size_t)64 * 64;
    }
    {
        int cid = t + 512, row = cid >> 4, ch = (cid & 15) ^ (row & 7);
        kSrc1 = (ch < 8) ? knope + (size_t)(b * S_ + row) * 1024 + h * 64 + ch * 8
                         : kr + (size_t)(b * S_ + row) * 64 + (ch - 8) * 8;
        kStp1 = (ch < 8) ? (size_t)64 * 1024 : (size_t)64 * 64;
    }
    {
        const bf16* Vg = Vt + (size_t)bh * 128 * S_;
        int cid = t, row = cid >> 3, ch = (cid & 7) ^ (row & 7);
        vSrc0 = Vg + (size_t)row * S_ + ch * 8;
        cid = t + 512; row = cid >> 3; ch = (cid & 7) ^ (row & 7);
        vSrc1 = Vg + (size_t)row * S_ + ch * 8;
    }
    auto stage = [&]() {
        gl2lds16(kSrc0, reinterpret_cast<char*>(Ks) + t * 16);
        gl2lds16(kSrc1, reinterpret_cast<char*>(Ks) + (t + 512) * 16);
        gl2lds16(vSrc0, reinterpret_cast<char*>(Vs) + t * 16);
        gl2lds16(vSrc1, reinterpret_cast<char*>(Vs) + (t + 512) * 16);
        kSrc0 += kStp0; kSrc1 += kStp1; vSrc0 += 64; vSrc1 += 64;
    };

    stage();

    f32x4 o[8] = {};
    float m_r = -1e30f, l_r = 0.f;                 // per-lane: q-row = r0 + l15

    for (int kb = 0; kb < NT; ++kb) {
        const int k0 = kb * 64;
        __syncthreads();                           // staged loads landed, all waves ready

        if (k0 <= r0 + 15) {                       // skip fully-masked tiles for this wave
            // S^T strip = K(64x128) @ Q^T(128x16): lane holds q=r0+l15,
            // k = k0 + m*16 + l4*4 + j   (log2 domain via pre-scaled Q)
            f32x4 sfr[4] = {};
            __builtin_amdgcn_s_setprio(1);
            #pragma unroll
            for (int kk = 0; kk < 4; ++kk) {
                short8 kf[4];
                #pragma unroll
                for (int m = 0; m < 4; ++m) {
                    int row = m * 16 + l15;
                    int ch = (kk * 4 + l4) ^ (row & 7);
                    kf[m] = *reinterpret_cast<const short8*>(
                        reinterpret_cast<const char*>(Ks) + row * 256 + ch * 16);
                }
                #pragma unroll
                for (int m = 0; m < 4; ++m)
                    sfr[m] = __builtin_amdgcn_mfma_f32_16x16x32_bf16(kf[m], qa_[kk], sfr[m], 0, 0, 0);
            }
            __builtin_amdgcn_s_setprio(0);

            const int qrow = r0 + l15;
            if (k0 + 63 > r0) {                    // causal mask (k > q)
                #pragma unroll
                for (int m = 0; m < 4; ++m) {
                    int kbase = k0 + m * 16 + l4 * 4;
                    #pragma unroll
                    for (int j = 0; j < 4; ++j)
                        if (kbase + j > qrow) sfr[m][j] = -1e30f;
                }
            }

            // row max: in-lane tree over 16 + 2 shfl across the l4 group
            float rm;
            {
                float a0 = fmaxf(fmaxf(sfr[0][0], sfr[0][1]), fmaxf(sfr[0][2], sfr[0][3]));
                float a1 = fmaxf(fmaxf(sfr[1][0], sfr[1][1]), fmaxf(sfr[1][2], sfr[1][3]));
                float a2 = fmaxf(fmaxf(sfr[2][0], sfr[2][1]), fmaxf(sfr[2][2], sfr[2][3]));
                float a3 = fmaxf(fmaxf(sfr[3][0], sfr[3][1]), fmaxf(sfr[3][2], sfr[3][3]));
                rm = fmaxf(fmaxf(a0, a1), fmaxf(a2, a3));
            }
            rm = fmaxf(rm, __shfl_xor(rm, 16));
            rm = fmaxf(rm, __shfl_xor(rm, 32));

            // defer-rescale (T13, THR=8 in log2 domain)
            if (__ballot(rm > m_r + 8.0f)) {
                float mn = fmaxf(m_r, rm);
                float alpha = exp2f(m_r - mn);
                m_r = mn;
                l_r *= alpha;
                float aj[4];
                #pragma unroll
                for (int j = 0; j < 4; ++j) aj[j] = __shfl(alpha, l4 * 4 + j);
                #pragma unroll
                for (int n = 0; n < 8; ++n)
                    #pragma unroll
                    for (int j = 0; j < 4; ++j) o[n][j] *= aj[j];
            }

            // P = exp2(S - m), pack pairs, one ds_write_b64 per m-frag
            char* pb = reinterpret_cast<char*>(Ps[w]);
            float rs = 0.f;
            #pragma unroll
            for (int m = 0; m < 4; ++m) {
                float p0 = exp2f(sfr[m][0] - m_r);
                float p1 = exp2f(sfr[m][1] - m_r);
                float p2 = exp2f(sfr[m][2] - m_r);
                float p3 = exp2f(sfr[m][3] - m_r);
                rs += (p0 + p1) + (p2 + p3);
                union { __hip_bfloat162 h; unsigned int u; } cl, ch2;
                cl.h  = __float22bfloat162_rn(make_float2(p0, p1));
                ch2.h = __float22bfloat162_rn(make_float2(p2, p3));
                int kloc = m * 16 + l4 * 4;
                int chnk = (kloc >> 3) ^ (l15 & 7);
                uint2 pk2; pk2.x = cl.u; pk2.y = ch2.u;
                *reinterpret_cast<uint2*>(pb + l15 * 128 + chnk * 16 + (kloc & 7) * 2) = pk2;
            }
            rs += __shfl_xor(rs, 16);
            rs += __shfl_xor(rs, 32);
            l_r += rs;

            // O += P(16x64) @ V(64x128)   (layout identical to prior rounds)
            __builtin_amdgcn_s_setprio(1);
            #pragma unroll
            for (int kk = 0; kk < 2; ++kk) {
                int pch = (kk * 4 + l4) ^ (l15 & 7);
                short8 pa = *reinterpret_cast<const short8*>(pb + l15 * 128 + pch * 16);
                #pragma unroll
                for (int n = 0; n < 8; ++n) {
                    int row = n * 16 + l15;
                    int ch = (kk * 4 + l4) ^ (row & 7);
                    short8 vb = *reinterpret_cast<const short8*>(
                        reinterpret_cast<const char*>(Vs) + row * 128 + ch * 16);
                    o[n] = __builtin_amdgcn_mfma_f32_16x16x32_bf16(pa, vb, o[n], 0, 0, 0);
                }
            }
            __builtin_amdgcn_s_setprio(0);
        }
        __syncthreads();                           // all waves done reading Ks/Vs
        if (kb + 1 < NT) stage();                  // overwrite for next tile
    }

    // l_r lives at lane with l15 == q-local; o[n][j] is q-local = l4*4+j
    float rj[4];
    #pragma unroll
    for (int j = 0; j < 4; ++j) rj[j] = __builtin_amdgcn_rcpf(__shfl(l_r, l4 * 4 + j));
    size_t obase = ((size_t)(b * S_) + r0) * (size_t)(NH_ * VDIM_) + h * VDIM_;
    #pragma unroll
    for (int n = 0; n < 8; ++n)
        #pragma unroll
        for (int j = 0; j < 4; ++j) {
            int r = l4 * 4 + j;
            int c = n * 16 + l15;
            attn_out[obase + (size_t)r * (NH_ * VDIM_) + c] = __float2bfloat16(o[n][j] * rj[j]);
        }
}

// ==============================================================================
extern "C" void kernel_launch(void* const* d_in, const int* in_sizes, int n_in,
                              void* d_out, int out_size, void* d_ws, size_t ws_size,
                              hipStream_t stream)
{
    (void)in_sizes; (void)n_in; (void)out_size;
    const float* x       = (const float*)d_in[0];
    const float* q_a_w   = (const float*)d_in[1];
    const float* q_a_ln  = (const float*)d_in[2];
    const float* q_b_w   = (const float*)d_in[3];
    const float* kv_a_w  = (const float*)d_in[4];
    const float* kv_a_ln = (const float*)d_in[5];
    const float* kv_b_w  = (const float*)d_in[6];
    const float* o_w     = (const float*)d_in[7];
    float* out = (float*)d_out;

    char* ws = (char*)d_ws;
    size_t off = 0;
    auto alloc = [&](size_t bytes) -> char* {
        char* p = ws + off;
        off += (bytes + 255) & ~(size_t)255;
        return p;
    };

    bf16* xb     = (bf16*)alloc((size_t)BS_ * HID_ * 2);        // reused as Qf after gemm_a
    bf16* a_wt   = (bf16*)alloc((size_t)NA_ * HID_ * 2);        // merged [q_a | kv_a]^T
    bf16* qb_wt  = (bf16*)alloc((size_t)2048 * QLORA_P * 2);    // qln folded
    bf16* kvb_wt = (bf16*)alloc((size_t)3072 * KVLORA_ * 2);    // permuted cols, kvln folded
    bf16* ow_t   = (bf16*)alloc((size_t)2048 * 2048 * 2);
    float* ct    = (float*)alloc((size_t)S_ * 32 * 4);
    float* st    = (float*)alloc((size_t)S_ * 32 * 4);
    bf16* qac    = (bf16*)alloc((size_t)BS_ * NA_ * 2);         // down-proj out [qa|ckvkpe]
    float* qsum  = (float*)alloc((size_t)8192 * 4);             // [qsum 4096 | ksum 4096]
    float* ksum  = qsum + BS_;
    bf16* kr     = (bf16*)alloc((size_t)BS_ * 64 * 2);
    bf16* knope  = (bf16*)alloc((size_t)BS_ * 1024 * 2);
    bf16* Vt     = (bf16*)alloc((size_t)BS_ * 2048 * 2);        // [bh][128][S]
    bf16* attn   = (bf16*)alloc((size_t)BS_ * 2048 * 2);

    bf16* Qf = xb;   // xb dead after gemm_a

    if (ws_size < off) return;  // diagnostic guard: absmax would stay exactly 3.468750

    // stage 0: merged prep (transposes + ln-fold + x convert + tables + sum-zero)
    TDs P;
    //              src      dst                   colw     Ksrc  Nsrc  Kpad  tX  off   perm
    P.d[0] = TD{ q_a_w,  a_wt,                     nullptr, 2048,  682, 2048, 64,    0, 0 };
    P.d[1] = TD{ kv_a_w, a_wt + (size_t)NQA_P*2048,nullptr, 2048,  320, 2048, 64, 1536, 0 };
    P.d[2] = TD{ q_b_w,  qb_wt,                    q_a_ln,   682, 2048,  704, 22, 2304, 0 };
    P.d[3] = TD{ kv_b_w, kvb_wt,                   kv_a_ln,  256, 3072,  256,  8, 3712, 1 };
    P.d[4] = TD{ o_w,    ow_t,                     nullptr, 2048, 2048, 2048, 64, 4480, 0 };
    k_prep<<<PREP_TILES + 8192 + 256 + 8, dim3(32, 8), 0, stream>>>(P, x, xb, ct, st, qsum);

    // stage 1: down-projection + fused rms-sums (atomic) + kpe rope
    gemm_a<<<dim3(NA_ / 128, BS_ / 128), 256, 0, stream>>>(xb, a_wt, qac, ct, st,
                                                           qsum, ksum, kr);

    // stage 2: merged up-projections with inline rsqrt + fused epilogues
    gemm_up<<<dim3(16 + 24, BS_ / 128), 256, 0, stream>>>(qac, qb_wt, ct, st, qsum, Qf,
                                                          kvb_wt, ksum, knope, Vt);

    // stage 3: causal flash attention (balanced strip-pairs, single-buffer K/V)
    k_flash<<<dim3(B_ * NH_, 16), 512, 0, stream>>>(Qf, knope, kr, Vt, attn);

    // stage 4: output projection (f32 out)
    gemm_bt<float><<<dim3(2048 / 128, BS_ / 128), 256, 0, stream>>>(attn, ow_t, out,
                                                                    HID_, HID_, HID_, 2048);
}